// Round 12
// baseline (2665.529 us; speedup 1.0000x reference)
//
#include <hip/hip_runtime.h>
#include <cstddef>

#define BB 4
#define TT 1024
#define DMODEL 512
#define DFF 2048
#define NHEAD 8
#define HDIM 64
#define NTOK (BB*TT)
#define NLAYER 6
#define MFOUT 256
#define LDS_STRIDE 72
#define SPLITK 4   // attention K-split: 4 chunks of 4 k-tiles each

typedef __attribute__((ext_vector_type(8))) _Float16 f16x8;
typedef __attribute__((ext_vector_type(8))) short bf16x8;
typedef __attribute__((ext_vector_type(4))) float f32x4;
#define MFMAH(a,b,c) __builtin_amdgcn_mfma_f32_16x16x32_f16(a,b,c,0,0,0)
#define MFMAB(a,b,c) __builtin_amdgcn_mfma_f32_16x16x32_bf16(a,b,c,0,0,0)

union F16U { _Float16 h; unsigned short u; };

__device__ __forceinline__ unsigned f2bf(float f) {
    union { float f; unsigned u; } v; v.f = f;
    return (v.u + 0x7FFFu + ((v.u >> 16) & 1u)) >> 16;
}
__device__ __forceinline__ float bf2f(unsigned h) {
    union { unsigned u; float f; } v; v.u = h << 16;
    return v.f;
}
__device__ __forceinline__ unsigned short f16u(float v) {
    F16U t; t.h = (_Float16)v; return t.u;
}

#define MODE_F32  0   // fp32 out (+optional res)
#define MODE_BF   1   // bf16 hi/lo pair
#define MODE_QKV  5   // gn<512: Q(f16 hi+mid*1024); <1024: K(f16); else V TRANSPOSED (f16 hi/lo planes)

// ---------------- weight convert: fp32 [K][N] -> bf16 hi/lo [N][K] ----------------
__global__ __launch_bounds__(256)
void wcvt(const float* __restrict__ W, unsigned short* __restrict__ Wh,
          unsigned short* __restrict__ Wl, int N, int K)
{
    __shared__ unsigned short Hs[64][LDS_STRIDE];
    __shared__ unsigned short Ls[64][LDS_STRIDE];
    const int tid = threadIdx.x;
    const int n0 = blockIdx.x * 64, k0 = blockIdx.y * 64;
    #pragma unroll
    for (int i = 0; i < 4; i++) {
        const int idx = tid + i * 256;
        const int r = idx >> 4, c4 = (idx & 15) * 4;
        const float4 v = *(const float4*)&W[(size_t)(k0 + r) * N + n0 + c4];
        const float va[4] = {v.x, v.y, v.z, v.w};
        #pragma unroll
        for (int j = 0; j < 4; j++) {
            const unsigned h = f2bf(va[j]);
            Hs[c4 + j][r] = (unsigned short)h;
            Ls[c4 + j][r] = (unsigned short)f2bf(va[j] - bf2f(h));
        }
    }
    __syncthreads();
    #pragma unroll
    for (int i = 0; i < 2; i++) {
        const int idx = tid + i * 256;
        const int r = idx >> 3, c8 = (idx & 7) * 8;
        *(uint4*)&Wh[(size_t)(n0 + r) * K + k0 + c8] = *(const uint4*)&Hs[r][c8];
        *(uint4*)&Wl[(size_t)(n0 + r) * K + k0 + c8] = *(const uint4*)&Ls[r][c8];
    }
}

// ------- epilogue shared by both GEMM kernels (gmb/gn computed by caller) -------
__device__ __forceinline__ void gemm_epilogue(
    int mode, int gmb, int gn, int N, const float* bias, const float* alpha,
    float alv, const f32x4& a, const float* __restrict__ res, float* __restrict__ outf,
    unsigned short* __restrict__ o1, unsigned short* __restrict__ o2,
    unsigned short* __restrict__ o3, unsigned short* __restrict__ o4,
    unsigned short* __restrict__ o5)
{
    const float bv = bias ? bias[gn] : 0.f;
    float v4[4];
    #pragma unroll
    for (int r = 0; r < 4; r++) {
        float v = a[r] + bv;
        if (alpha) v = (v >= 0.f) ? v : alv * v;
        v4[r] = v;
    }
    if (mode == MODE_F32) {
        #pragma unroll
        for (int r = 0; r < 4; r++) {
            const size_t oix = (size_t)(gmb + r) * N + gn;
            outf[oix] = v4[r] + (res ? res[oix] : 0.f);
        }
    } else if (mode == MODE_BF) {
        #pragma unroll
        for (int r = 0; r < 4; r++) {
            const size_t oix = (size_t)(gmb + r) * N + gn;
            const unsigned h = f2bf(v4[r]);
            o1[oix] = (unsigned short)h;
            o2[oix] = (unsigned short)f2bf(v4[r] - bf2f(h));
        }
    } else { // MODE_QKV
        const int seg = gn >> 9;
        if (seg == 0) {
            #pragma unroll
            for (int r = 0; r < 4; r++) {
                const size_t qix = (size_t)(gmb + r) * 512 + gn;
                F16U t; t.h = (_Float16)v4[r];
                o1[qix] = t.u;
                o2[qix] = f16u((v4[r] - (float)t.h) * 1024.f);
            }
        } else if (seg == 1) {
            #pragma unroll
            for (int r = 0; r < 4; r++)
                o3[(size_t)(gmb + r) * 512 + (gn - 512)] = f16u(v4[r]);
        } else {
            // V transposed: planes [(bb*8+h)*64 + d][t], 4 consecutive t -> 8B store
            const int d512 = gn - 1024;
            const int bbp = gmb >> 10, t0 = gmb & 1023;
            const size_t vix = ((size_t)(bbp * 8 + (d512 >> 6)) * 64 + (d512 & 63)) * 1024 + t0;
            ushort4 hv, lv;
            unsigned short* hp = (unsigned short*)&hv;
            unsigned short* lp = (unsigned short*)&lv;
            #pragma unroll
            for (int r = 0; r < 4; r++) {
                F16U t; t.h = (_Float16)v4[r];
                hp[r] = t.u;
                lp[r] = f16u(v4[r] - (float)t.h);
            }
            *(ushort4*)&o4[vix] = hv;
            *(ushort4*)&o5[vix] = lv;
        }
    }
}

// ---------------- 64x64-tile pair GEMM (all N=512 shapes + dec2) ----------------
__global__ __launch_bounds__(256)
void gemm_l(const unsigned short* __restrict__ Ah, const unsigned short* __restrict__ Al,
            const unsigned short* __restrict__ Wh, const unsigned short* __restrict__ Wl,
            const float* __restrict__ bias, const float* __restrict__ alpha,
            const float* __restrict__ res, float* __restrict__ outf,
            unsigned short* __restrict__ o1, unsigned short* __restrict__ o2,
            unsigned short* __restrict__ o3, unsigned short* __restrict__ o4,
            unsigned short* __restrict__ o5, int N, int K, int mode)
{
    __shared__ __align__(16) unsigned short Ahs[64*LDS_STRIDE];
    __shared__ __align__(16) unsigned short Als[64*LDS_STRIDE];
    __shared__ __align__(16) unsigned short Whs[64*LDS_STRIDE];
    __shared__ __align__(16) unsigned short Wls[64*LDS_STRIDE];
    const int tid = threadIdx.x;
    const int lane = tid & 63, w = tid >> 6;
    const int wm = w >> 1, wn = w & 1;
    const int quad = lane >> 4, c = lane & 15;
    const int m0 = blockIdx.y * 64, n0 = blockIdx.x * 64;
    const int sr = tid >> 2, sc = (tid & 3) * 16;

    f32x4 acc[2][2];
    #pragma unroll
    for (int mi = 0; mi < 2; mi++)
        #pragma unroll
        for (int ni = 0; ni < 2; ni++) { acc[mi][ni][0]=0.f; acc[mi][ni][1]=0.f; acc[mi][ni][2]=0.f; acc[mi][ni][3]=0.f; }

    for (int k0 = 0; k0 < K; k0 += 64) {
        const size_t ga = (size_t)(m0 + sr) * K + k0 + sc;
        const size_t gb = (size_t)(n0 + sr) * K + k0 + sc;
        const int ls = sr * LDS_STRIDE + sc;
        *(uint4*)&Ahs[ls]     = *(const uint4*)&Ah[ga];
        *(uint4*)&Ahs[ls + 8] = *(const uint4*)&Ah[ga + 8];
        *(uint4*)&Als[ls]     = *(const uint4*)&Al[ga];
        *(uint4*)&Als[ls + 8] = *(const uint4*)&Al[ga + 8];
        *(uint4*)&Whs[ls]     = *(const uint4*)&Wh[gb];
        *(uint4*)&Whs[ls + 8] = *(const uint4*)&Wh[gb + 8];
        *(uint4*)&Wls[ls]     = *(const uint4*)&Wl[gb];
        *(uint4*)&Wls[ls + 8] = *(const uint4*)&Wl[gb + 8];
        __syncthreads();
        #pragma unroll
        for (int s = 0; s < 2; s++) {
            const int ao = (wm * 32 + c) * LDS_STRIDE + s * 32 + quad * 8;
            const int bo = (wn * 32 + c) * LDS_STRIDE + s * 32 + quad * 8;
            const bf16x8 ah0 = *(const bf16x8*)&Ahs[ao];
            const bf16x8 ah1 = *(const bf16x8*)&Ahs[ao + 16 * LDS_STRIDE];
            const bf16x8 al0 = *(const bf16x8*)&Als[ao];
            const bf16x8 al1 = *(const bf16x8*)&Als[ao + 16 * LDS_STRIDE];
            const bf16x8 bh0 = *(const bf16x8*)&Whs[bo];
            const bf16x8 bh1 = *(const bf16x8*)&Whs[bo + 16 * LDS_STRIDE];
            const bf16x8 bl0 = *(const bf16x8*)&Wls[bo];
            const bf16x8 bl1 = *(const bf16x8*)&Wls[bo + 16 * LDS_STRIDE];
            acc[0][0] = MFMAB(ah0, bh0, acc[0][0]);
            acc[0][1] = MFMAB(ah0, bh1, acc[0][1]);
            acc[1][0] = MFMAB(ah1, bh0, acc[1][0]);
            acc[1][1] = MFMAB(ah1, bh1, acc[1][1]);
            acc[0][0] = MFMAB(al0, bh0, acc[0][0]);
            acc[0][1] = MFMAB(al0, bh1, acc[0][1]);
            acc[1][0] = MFMAB(al1, bh0, acc[1][0]);
            acc[1][1] = MFMAB(al1, bh1, acc[1][1]);
            acc[0][0] = MFMAB(ah0, bl0, acc[0][0]);
            acc[0][1] = MFMAB(ah0, bl1, acc[0][1]);
            acc[1][0] = MFMAB(ah1, bl0, acc[1][0]);
            acc[1][1] = MFMAB(ah1, bl1, acc[1][1]);
        }
        __syncthreads();
    }
    const float alv = alpha ? alpha[0] : 0.f;
    #pragma unroll
    for (int mi = 0; mi < 2; mi++)
        #pragma unroll
        for (int ni = 0; ni < 2; ni++) {
            const int gn = n0 + wn * 32 + ni * 16 + c;
            const int gmb = m0 + wm * 32 + mi * 16 + quad * 4;
            gemm_epilogue(mode, gmb, gn, N, bias, alpha, alv, acc[mi][ni],
                          res, outf, o1, o2, o3, o4, o5);
        }
}

// ---------------- 128x128-tile pair GEMM with staging prefetch ------------------
// R9 lesson: 128^2 only where grid >= ~512 blocks (FFN1: 512, QKV: 384); N=512
// shapes stay on gemm_l (R9's 128-block grids left half the GPU idle at 5.5% occ).
// Added: register prefetch of next K-tile (attn-R7 pattern) — 16 uint4 issued
// right after the first barrier so global latency hides under the 96-MFMA
// compute phase. VGPR: acc 64 + frags 64 + prefetch 64 ~ 200 < 256 (launch
// bounds (256,2) budget), no spill.
__global__ __launch_bounds__(256, 2)
void gemm_l2(const unsigned short* __restrict__ Ah, const unsigned short* __restrict__ Al,
             const unsigned short* __restrict__ Wh, const unsigned short* __restrict__ Wl,
             const float* __restrict__ bias, const float* __restrict__ alpha,
             const float* __restrict__ res, float* __restrict__ outf,
             unsigned short* __restrict__ o1, unsigned short* __restrict__ o2,
             unsigned short* __restrict__ o3, unsigned short* __restrict__ o4,
             unsigned short* __restrict__ o5, int N, int K, int mode)
{
    __shared__ __align__(16) unsigned short Ahs[128*LDS_STRIDE];
    __shared__ __align__(16) unsigned short Als[128*LDS_STRIDE];
    __shared__ __align__(16) unsigned short Whs[128*LDS_STRIDE];
    __shared__ __align__(16) unsigned short Wls[128*LDS_STRIDE];
    const int tid = threadIdx.x;
    const int lane = tid & 63, w = tid >> 6;
    const int wm = w >> 1, wn = w & 1;            // 2x2 wave grid, wave = 64x64
    const int quad = lane >> 4, c = lane & 15;
    const int m0 = blockIdx.y * 128, n0 = blockIdx.x * 128;
    const int sr = tid >> 1, sc = (tid & 1) * 32; // stage: 2 threads/row, 32 shorts each

    f32x4 acc[4][4];
    #pragma unroll
    for (int mi = 0; mi < 4; mi++)
        #pragma unroll
        for (int ni = 0; ni < 4; ni++) { acc[mi][ni][0]=0.f; acc[mi][ni][1]=0.f; acc[mi][ni][2]=0.f; acc[mi][ni][3]=0.f; }

    // prefetch K-tile 0
    uint4 pah[4], pal[4], pwh[4], pwl[4];
    {
        const size_t ga = (size_t)(m0 + sr) * K + sc;
        const size_t gb = (size_t)(n0 + sr) * K + sc;
        #pragma unroll
        for (int j = 0; j < 4; j++) {
            pah[j] = *(const uint4*)&Ah[ga + 8*j];
            pal[j] = *(const uint4*)&Al[ga + 8*j];
            pwh[j] = *(const uint4*)&Wh[gb + 8*j];
            pwl[j] = *(const uint4*)&Wl[gb + 8*j];
        }
    }
    for (int k0 = 0; k0 < K; k0 += 64) {
        const int ls = sr * LDS_STRIDE + sc;
        #pragma unroll
        for (int j = 0; j < 4; j++) {
            *(uint4*)&Ahs[ls + 8*j] = pah[j];
            *(uint4*)&Als[ls + 8*j] = pal[j];
            *(uint4*)&Whs[ls + 8*j] = pwh[j];
            *(uint4*)&Wls[ls + 8*j] = pwl[j];
        }
        __syncthreads();
        // prefetch next K-tile (clamped; last iteration's prefetch unused)
        {
            const int kn = (k0 + 64 < K) ? k0 + 64 : k0;
            const size_t ga = (size_t)(m0 + sr) * K + kn + sc;
            const size_t gb = (size_t)(n0 + sr) * K + kn + sc;
            #pragma unroll
            for (int j = 0; j < 4; j++) {
                pah[j] = *(const uint4*)&Ah[ga + 8*j];
                pal[j] = *(const uint4*)&Al[ga + 8*j];
                pwh[j] = *(const uint4*)&Wh[gb + 8*j];
                pwl[j] = *(const uint4*)&Wl[gb + 8*j];
            }
        }
        #pragma unroll
        for (int s = 0; s < 2; s++) {
            bf16x8 ah[4], al[4], bh[4], bl[4];
            #pragma unroll
            for (int i = 0; i < 4; i++) {
                const int ao = (wm * 64 + i * 16 + c) * LDS_STRIDE + s * 32 + quad * 8;
                const int bo = (wn * 64 + i * 16 + c) * LDS_STRIDE + s * 32 + quad * 8;
                ah[i] = *(const bf16x8*)&Ahs[ao];
                al[i] = *(const bf16x8*)&Als[ao];
                bh[i] = *(const bf16x8*)&Whs[bo];
                bl[i] = *(const bf16x8*)&Wls[bo];
            }
            #pragma unroll
            for (int mi = 0; mi < 4; mi++)
                #pragma unroll
                for (int ni = 0; ni < 4; ni++) {
                    acc[mi][ni] = MFMAB(ah[mi], bh[ni], acc[mi][ni]);
                    acc[mi][ni] = MFMAB(al[mi], bh[ni], acc[mi][ni]);
                    acc[mi][ni] = MFMAB(ah[mi], bl[ni], acc[mi][ni]);
                }
        }
        __syncthreads();
    }
    const float alv = alpha ? alpha[0] : 0.f;
    #pragma unroll
    for (int mi = 0; mi < 4; mi++)
        #pragma unroll
        for (int ni = 0; ni < 4; ni++) {
            const int gn = n0 + wn * 64 + ni * 16 + c;
            const int gmb = m0 + wm * 64 + mi * 16 + quad * 4;
            gemm_epilogue(mode, gmb, gn, N, bias, alpha, alv, acc[mi][ni],
                          res, outf, o1, o2, o3, o4, o5);
        }
}

// ---------------- LayerNorm: one wave per token -> bf16 hi/lo pair ----------------
__global__ __launch_bounds__(64)
void ln_kernel(const float* __restrict__ x, const float* __restrict__ g,
               const float* __restrict__ b, unsigned short* __restrict__ oh,
               unsigned short* __restrict__ ol)
{
    const int token = blockIdx.x;
    const int lane = threadIdx.x;
    const float* row = x + (size_t)token * DMODEL;
    float v[8];
    *(float4*)&v[0] = *(const float4*)&row[lane * 4];
    *(float4*)&v[4] = *(const float4*)&row[256 + lane * 4];
    float s = 0.f, s2 = 0.f;
    #pragma unroll
    for (int i = 0; i < 8; i++) { s += v[i]; s2 += v[i] * v[i]; }
    #pragma unroll
    for (int off = 1; off < 64; off <<= 1) {
        s  += __shfl_xor(s, off);
        s2 += __shfl_xor(s2, off);
    }
    const float mean = s * (1.f / DMODEL);
    const float var  = s2 * (1.f / DMODEL) - mean * mean;
    const float rstd = rsqrtf(var + 1e-5f);
    #pragma unroll
    for (int hh = 0; hh < 2; hh++) {
        const int base = hh * 256 + lane * 4;
        const float4 gv = *(const float4*)&g[base];
        const float4 bv = *(const float4*)&b[base];
        float o[4];
        o[0] = (v[hh*4+0] - mean) * rstd * gv.x + bv.x;
        o[1] = (v[hh*4+1] - mean) * rstd * gv.y + bv.y;
        o[2] = (v[hh*4+2] - mean) * rstd * gv.z + bv.z;
        o[3] = (v[hh*4+3] - mean) * rstd * gv.w + bv.w;
        ushort4 ph, pl;
        unsigned short* php = (unsigned short*)&ph;
        unsigned short* plp = (unsigned short*)&pl;
        #pragma unroll
        for (int j = 0; j < 4; j++) {
            const unsigned hb = f2bf(o[j]);
            php[j] = (unsigned short)hb;
            plp[j] = (unsigned short)f2bf(o[j] - bf2f(hb));
        }
        *(ushort4*)&oh[(size_t)token * DMODEL + base] = ph;
        *(ushort4*)&ol[(size_t)token * DMODEL + base] = pl;
    }
}

// ---------------- fp32 -> bf16 hi/lo pair (elementwise) ----------------
__global__ __launch_bounds__(256)
void cvt_pair(const float* __restrict__ x, unsigned short* __restrict__ oh,
              unsigned short* __restrict__ ol)
{
    const int idx = (blockIdx.x * 256 + threadIdx.x) * 4;
    const float4 v = *(const float4*)&x[idx];
    const float va[4] = {v.x, v.y, v.z, v.w};
    ushort4 ph, pl;
    unsigned short* php = (unsigned short*)&ph;
    unsigned short* plp = (unsigned short*)&pl;
    #pragma unroll
    for (int j = 0; j < 4; j++) {
        const unsigned hb = f2bf(va[j]);
        php[j] = (unsigned short)hb;
        plp[j] = (unsigned short)f2bf(va[j] - bf2f(hb));
    }
    *(ushort4*)&oh[idx] = ph;
    *(ushort4*)&ol[idx] = pl;
}

// ---------------- concat [x | mask] -> bf16 pair, [4096][1024] ----------------
__global__ __launch_bounds__(256)
void cvt_cat(const float* __restrict__ x, const float* __restrict__ mask,
             unsigned short* __restrict__ oh, unsigned short* __restrict__ ol)
{
    const int idx = (blockIdx.x * 256 + threadIdx.x) * 4;
    const int row = idx >> 10, col = idx & 1023;
    const float* src = (col < 512) ? &x[(size_t)row * 512 + col]
                                   : &mask[(size_t)row * 512 + col - 512];
    const float4 v = *(const float4*)src;
    const float va[4] = {v.x, v.y, v.z, v.w};
    ushort4 ph, pl;
    unsigned short* php = (unsigned short*)&ph;
    unsigned short* plp = (unsigned short*)&pl;
    #pragma unroll
    for (int j = 0; j < 4; j++) {
        const unsigned hb = f2bf(va[j]);
        php[j] = (unsigned short)hb;
        plp[j] = (unsigned short)f2bf(va[j] - bf2f(hb));
    }
    *(ushort4*)&oh[idx] = ph;
    *(ushort4*)&ol[idx] = pl;
}

// ---------------- attention key-validity mask ----------------
__global__ __launch_bounds__(64)
void mask_kernel(const float* __restrict__ mask_in, float* __restrict__ mk)
{
    const int token = blockIdx.x;
    const int lane = threadIdx.x;
    const float* row = mask_in + (size_t)token * DMODEL;
    const float4 a = *(const float4*)&row[lane * 4];
    const float4 c = *(const float4*)&row[256 + lane * 4];
    float s = a.x + a.y + a.z + a.w + c.x + c.y + c.z + c.w;
    #pragma unroll
    for (int off = 1; off < 64; off <<= 1) s += __shfl_xor(s, off);
    if (lane == 0) mk[token] = (s > 0.f) ? 0.f : -1e9f;
}

// ---------------- relative position table E -> TILED f16 hi/lo ----------------
// Tiled layout for coalesced wave-loads in attn: for 16-row block g and s in {0,1},
//   Et[((g*2+s)*64 + l)*8 + j] = E[16*g + (l&15)][(l>>4)*8 + s*32 + j]
// so a wave (lane=l) fragment load is 1024B CONTIGUOUS. 2048 rows; row 2047
// duplicates row 2046 so the attn index gr in [0,2047] needs no clamp.
__global__ __launch_bounds__(64)
void e_kernel(const float* __restrict__ w1, const float* __restrict__ b1,
              const float* __restrict__ a1, const float* __restrict__ w2,
              const float* __restrict__ b2,
              unsigned short* __restrict__ Ehi, unsigned short* __restrict__ Elo)
{
    __shared__ float t1[DMODEL];
    const int r = blockIdx.x;              // 0..2047
    const int rr = (r > 2046) ? 2046 : r;  // row 2047 = copy of 2046
    const int lane = threadIdx.x;          // col 0..63
    const float rel = (float)rr - 1023.f;
    const float al = a1[0];
    for (int j = lane; j < DMODEL; j += 64) {
        float v = rel * w1[j] + b1[j];
        t1[j] = (v >= 0.f) ? v : al * v;
    }
    __syncthreads();
    float acc = b2[lane];
    for (int j = 0; j < DMODEL; j++)
        acc = fmaf(t1[j], w2[j * HDIM + lane], acc);
    // tiled address for (row=r, col=lane)
    const int g = r >> 4, s = lane >> 5;
    const int l = (((lane >> 3) & 3) << 4) | (r & 15);
    const int j = lane & 7;
    const size_t adr = ((size_t)(g * 2 + s) * 64 + l) * 8 + j;
    F16U t; t.h = (_Float16)acc;
    Ehi[adr] = t.u;
    Elo[adr] = f16u(acc - (float)t.h);
}

// ---------------- keyframe encoder layer 1 (K=2) -> bf16 pair ----------------
__global__ __launch_bounds__(256)
void kf1_kernel(const float* __restrict__ p, const float* __restrict__ w1,
                const float* __restrict__ b1, const float* __restrict__ a1,
                unsigned short* __restrict__ oh, unsigned short* __restrict__ ol)
{
    const int idx = blockIdx.x * 256 + threadIdx.x;
    const int m = idx >> 9, n = idx & 511;
    float v = fmaf(p[m*2], w1[n], fmaf(p[m*2+1], w1[DMODEL + n], b1[n]));
    v = (v >= 0.f) ? v : a1[0] * v;
    const unsigned hb = f2bf(v);
    oh[idx] = (unsigned short)hb;
    ol[idx] = (unsigned short)f2bf(v - bf2f(hb));
}

// ---------------- MFMA flash attention: 128-row Q-block, 8 waves, split-K -------
// (unchanged from R8 — 85us/dispatch, spill-free, 2-chunk rel-term)
__global__ __launch_bounds__(512, 2)
void attn_mfma(const _Float16* __restrict__ qhg, const _Float16* __restrict__ qmg,
               const _Float16* __restrict__ kg, const _Float16* __restrict__ vth,
               const _Float16* __restrict__ vtl, const _Float16* __restrict__ Ehi,
               const _Float16* __restrict__ Elo, const float* __restrict__ mk,
               float* __restrict__ Opart, float* __restrict__ Mpart,
               float* __restrict__ Lpart)
{
    __shared__ __align__(16) _Float16 Ks [64*LDS_STRIDE];
    __shared__ __align__(16) _Float16 Vhs[64*LDS_STRIDE];
    __shared__ __align__(16) _Float16 Vls[64*LDS_STRIDE];
    __shared__ __align__(16) _Float16 Phs[128*LDS_STRIDE];
    __shared__ __align__(16) _Float16 Pls[128*LDS_STRIDE];

    const int tid = threadIdx.x;
    const int lane = tid & 63;
    const int w = tid >> 6;                 // 0..7
    const int quad = lane >> 4;
    const int c = lane & 15;
    const int q0 = (blockIdx.x >> 2) * 128; // 128-row q-block
    const int split = blockIdx.x & 3;
    const int hh = blockIdx.y;
    const int bb = blockIdx.z;
    const size_t base = (size_t)bb * TT * DMODEL + (size_t)hh * HDIM;
    const size_t vbase = (size_t)(bb * NHEAD + hh) * HDIM * TT;
    const float* mkp = mk + bb * TT;
    const int srow = tid >> 3;              // staging: 8 threads/row, 64 rows
    const int scol = (tid & 7) * 8;         // 16B each, 128B contiguous per row

    f16x8 qh[2], qm[2];
    {
        const size_t qrow = base + (size_t)(q0 + 16 * w + c) * DMODEL;
        #pragma unroll
        for (int s = 0; s < 2; s++) {
            qh[s] = *(const f16x8*)&qhg[qrow + s * 32 + quad * 8];
            qm[s] = *(const f16x8*)&qmg[qrow + s * 32 + quad * 8];
        }
    }

    f32x4 O[4];
    #pragma unroll
    for (int dt = 0; dt < 4; dt++) { O[dt][0]=0.f; O[dt][1]=0.f; O[dt][2]=0.f; O[dt][3]=0.f; }
    float mrun[4] = {-1e30f, -1e30f, -1e30f, -1e30f};
    float lrun[4] = {0.f, 0.f, 0.f, 0.f};
    const int Jb = 48 - 16 * w;             // negative for w>=4; gr stays >= 0

    const int ktlo = split * (16 / SPLITK);
    // prefetch tile ktlo staging into registers
    f16x8 sk, svh, svl;
    {
        const int k0 = ktlo * 64;
        sk  = *(const f16x8*)&kg [base + (size_t)(k0 + srow) * DMODEL + scol];
        svh = *(const f16x8*)&vth[vbase + (size_t)srow * TT + k0 + scol];
        svl = *(const f16x8*)&vtl[vbase + (size_t)srow * TT + k0 + scol];
    }
    for (int kt = ktlo; kt < ktlo + (16 / SPLITK); kt++) {
        const int k0 = kt * 64;
        const int rbase = k0 - q0 + 960;

        // write staged tile, then prefetch next tile's regs (flies under compute)
        *(f16x8*)&Ks [srow * LDS_STRIDE + scol] = sk;
        *(f16x8*)&Vhs[srow * LDS_STRIDE + scol] = svh;
        *(f16x8*)&Vls[srow * LDS_STRIDE + scol] = svl;
        __syncthreads();
        {
            const int kn = (kt + 1 < 16) ? (kt + 1) : kt;  // clamp: last prefetch unused
            const int k0n = kn * 64;
            sk  = *(const f16x8*)&kg [base + (size_t)(k0n + srow) * DMODEL + scol];
            svh = *(const f16x8*)&vth[vbase + (size_t)srow * TT + k0n + scol];
            svl = *(const f16x8*)&vtl[vbase + (size_t)srow * TT + k0n + scol];
        }

        // S = Q K^T (K fragments from LDS)
        f32x4 S[4];
        #pragma unroll
        for (int t = 0; t < 4; t++) { S[t][0]=0.f; S[t][1]=0.f; S[t][2]=0.f; S[t][3]=0.f; }
        #pragma unroll
        for (int t = 0; t < 4; t++) {
            const int ko = (16 * t + c) * LDS_STRIDE + quad * 8;
            #pragma unroll
            for (int s = 0; s < 2; s++) {
                const f16x8 kf = *(const f16x8*)&Ks[ko + s * 32];
                S[t] = MFMAH(qh[s], kf, S[t]);
            }
        }
        // rel term from TILED E, in two chunks (3u + 2u) to cap reg pressure.
        float bp[4][5];
        #pragma unroll
        for (int ch = 0; ch < 2; ch++) {
            const int u0 = ch * 3;
            const int nu = ch ? 2 : 3;
            f32x4 R[3], R2[3];
            #pragma unroll
            for (int v = 0; v < 3; v++) {
                if (v >= nu) continue;
                R[v][0]=0.f; R[v][1]=0.f; R[v][2]=0.f; R[v][3]=0.f;
                R2[v][0]=0.f; R2[v][1]=0.f; R2[v][2]=0.f; R2[v][3]=0.f;
            }
            #pragma unroll
            for (int v = 0; v < 3; v++) {
                if (v >= nu) continue;
                const int g = (rbase + Jb + 16 * (u0 + v)) >> 4;
                const size_t eb0 = ((size_t)(g * 2 + 0) * 64 + lane) * 8;
                const size_t eb1 = ((size_t)(g * 2 + 1) * 64 + lane) * 8;
                const f16x8 eh0 = *(const f16x8*)&Ehi[eb0];
                const f16x8 eh1 = *(const f16x8*)&Ehi[eb1];
                const f16x8 el0 = *(const f16x8*)&Elo[eb0];
                const f16x8 el1 = *(const f16x8*)&Elo[eb1];
                R[v]  = MFMAH(qh[0], eh0, R[v]);
                R[v]  = MFMAH(qh[1], eh1, R[v]);
                R[v]  = MFMAH(qh[0], el0, R[v]);
                R[v]  = MFMAH(qh[1], el1, R[v]);
                R2[v] = MFMAH(qm[0], eh0, R2[v]);
                R2[v] = MFMAH(qm[1], eh1, R2[v]);
            }
            #pragma unroll
            for (int v = 0; v < 3; v++) {
                if (v >= nu) continue;
                #pragma unroll
                for (int r = 0; r < 4; r++) {
                    const float rv = fmaf(R2[v][r], 9.765625e-4f, R[v][r]);
                    const int q = quad * 4 + r;
                    const int srcl = (quad << 4) | ((c - q + 15) & 15);
                    bp[r][u0 + v] = __int_as_float(__builtin_amdgcn_ds_bpermute(srcl << 2, __float_as_int(rv)));
                }
            }
        }
        float mkv[4];
        #pragma unroll
        for (int t = 0; t < 4; t++) mkv[t] = mkp[k0 + 16*t + c];
        float tmax[4] = {-3e38f, -3e38f, -3e38f, -3e38f};
        #pragma unroll
        for (int t = 0; t < 4; t++)
            #pragma unroll
            for (int r = 0; r < 4; r++) {
                const int q = quad*4 + r;
                const int jj = 16*t + c - q + 15;
                const float rv = ((jj >> 4) == t) ? bp[r][t] : bp[r][t+1];
                const float v = (S[t][r] + rv) * 0.125f + mkv[t];
                S[t][r] = v;
                tmax[r] = fmaxf(tmax[r], v);
            }
        #pragma unroll
        for (int r = 0; r < 4; r++) {
            tmax[r] = fmaxf(tmax[r], __shfl_xor(tmax[r], 1));
            tmax[r] = fmaxf(tmax[r], __shfl_xor(tmax[r], 2));
            tmax[r] = fmaxf(tmax[r], __shfl_xor(tmax[r], 4));
            tmax[r] = fmaxf(tmax[r], __shfl_xor(tmax[r], 8));
        }
        float corr[4];
        #pragma unroll
        for (int r = 0; r < 4; r++) {
            const float mn = fmaxf(mrun[r], tmax[r]);
            corr[r] = __expf(mrun[r] - mn);
            mrun[r] = mn;
            lrun[r] *= corr[r];
        }
        #pragma unroll
        for (int dt = 0; dt < 4; dt++)
            #pragma unroll
            for (int r = 0; r < 4; r++) O[dt][r] *= corr[r];
        float psum[4] = {0.f, 0.f, 0.f, 0.f};
        #pragma unroll
        for (int t = 0; t < 4; t++)
            #pragma unroll
            for (int r = 0; r < 4; r++) {
                const float p = __expf(S[t][r] - mrun[r]);
                psum[r] += p;
                const _Float16 hp = (_Float16)p;
                Phs[(w*16 + quad*4 + r)*LDS_STRIDE + 16*t + c] = hp;
                Pls[(w*16 + quad*4 + r)*LDS_STRIDE + 16*t + c] = (_Float16)(p - (float)hp);
            }
        #pragma unroll
        for (int r = 0; r < 4; r++) {
            psum[r] += __shfl_xor(psum[r], 1);
            psum[r] += __shfl_xor(psum[r], 2);
            psum[r] += __shfl_xor(psum[r], 4);
            psum[r] += __shfl_xor(psum[r], 8);
            lrun[r] += psum[r];
        }
        // P write -> P read: same-wave DS ordering + compiler-tracked aliasing
        // (fence-free correctness verified R5-R9).
        f16x8 pfh[2], pfl[2];
        #pragma unroll
        for (int s = 0; s < 2; s++) {
            pfh[s] = *(const f16x8*)&Phs[(w*16 + c)*LDS_STRIDE + s*32 + quad*8];
            pfl[s] = *(const f16x8*)&Pls[(w*16 + c)*LDS_STRIDE + s*32 + quad*8];
        }
        // O += P V (V fragments from LDS)
        #pragma unroll
        for (int dt = 0; dt < 4; dt++) {
            const int vo = (16 * dt + c) * LDS_STRIDE + quad * 8;
            #pragma unroll
            for (int s = 0; s < 2; s++) {
                const f16x8 vhf = *(const f16x8*)&Vhs[vo + s * 32];
                const f16x8 vlf = *(const f16x8*)&Vls[vo + s * 32];
                O[dt] = MFMAH(pfh[s], vhf, O[dt]);
                O[dt] = MFMAH(pfl[s], vhf, O[dt]);
                O[dt] = MFMAH(pfh[s], vlf, O[dt]);
            }
        }
        __syncthreads();   // all waves done with Ks/Vhs/Vls before next overwrite
    }
    // write partial: unnormalized O (f32) + m,l per q-row
    const size_t obase = (size_t)((split * BB + bb) * NHEAD + hh) * TT + q0 + 16 * w;
    #pragma unroll
    for (int r = 0; r < 4; r++) {
        if (c == 0) {
            Mpart[obase + quad * 4 + r] = mrun[r];
            Lpart[obase + quad * 4 + r] = lrun[r];
        }
    }
    #pragma unroll
    for (int dt = 0; dt < 4; dt++)
        #pragma unroll
        for (int r = 0; r < 4; r++)
            Opart[(obase + quad * 4 + r) * HDIM + 16 * dt + c] = O[dt][r];
}

// ---------------- combine SPLITK attention partials -> bf16 hi/lo ----------------
__global__ __launch_bounds__(256)
void attn_combine(const float* __restrict__ Opart, const float* __restrict__ Mpart,
                  const float* __restrict__ Lpart,
                  unsigned short* __restrict__ obh, unsigned short* __restrict__ obl)
{
    const int tid = threadIdx.x;
    const int row = blockIdx.x * 16 + (tid >> 4);   // (bb*H+hh)*T + q
    const int d0 = (tid & 15) * 4;
    const int SR = BB * NHEAD * TT;
    float mv[SPLITK];
    float m = -3e38f;
    #pragma unroll
    for (int i = 0; i < SPLITK; i++) { mv[i] = Mpart[i * SR + row]; m = fmaxf(m, mv[i]); }
    float wv[SPLITK];
    float l = 0.f;
    #pragma unroll
    for (int i = 0; i < SPLITK; i++) {
        wv[i] = __expf(mv[i] - m);
        l += wv[i] * Lpart[i * SR + row];
    }
    const float inv = 1.f / l;
    float o[4] = {0.f, 0.f, 0.f, 0.f};
    #pragma unroll
    for (int i = 0; i < SPLITK; i++) {
        const float4 v = *(const float4*)&Opart[((size_t)i * SR + row) * HDIM + d0];
        o[0] = fmaf(wv[i], v.x, o[0]);
        o[1] = fmaf(wv[i], v.y, o[1]);
        o[2] = fmaf(wv[i], v.z, o[2]);
        o[3] = fmaf(wv[i], v.w, o[3]);
    }
    const int q = row & (TT - 1), bh = row >> 10;
    const size_t oix = ((size_t)((bh >> 3) * TT + q)) * DMODEL + (size_t)(bh & 7) * HDIM + d0;
    ushort4 ph, pl;
    unsigned short* php = (unsigned short*)&ph;
    unsigned short* plp = (unsigned short*)&pl;
    #pragma unroll
    for (int j = 0; j < 4; j++) {
        const float v = o[j] * inv;
        const unsigned hb = f2bf(v);
        php[j] = (unsigned short)hb;
        plp[j] = (unsigned short)f2bf(v - bf2f(hb));
    }
    *(ushort4*)&obh[oix] = ph;
    *(ushort4*)&obl[oix] = pl;
}

extern "C" void kernel_launch(void* const* d_in, const int* in_sizes, int n_in,
                              void* d_out, int out_size, void* d_ws, size_t ws_size,
                              hipStream_t stream)
{
    const float* x       = (const float*)d_in[0];
    const float* mask_in = (const float*)d_in[1];
    const float* p_kf    = (const float*)d_in[2];
    const float* enc_w1  = (const float*)d_in[3];
    const float* enc_b1  = (const float*)d_in[4];
    const float* enc_a1  = (const float*)d_in[5];
    const float* enc_w2  = (const float*)d_in[6];
    const float* enc_b2  = (const float*)d_in[7];
    const float* enc_a2  = (const float*)d_in[8];
    const float* kf_w1   = (const float*)d_in[9];
    const float* kf_b1   = (const float*)d_in[10];
    const float* kf_a    = (const float*)d_in[11];
    const float* kf_w2   = (const float*)d_in[12];
    const float* kf_b2   = (const float*)d_in[13];
    const float* rel_w1  = (const float*)d_in[14];
    const float* rel_b1  = (const float*)d_in[15];
    const float* rel_a   = (const float*)d_in[16];
    const float* rel_w2  = (const float*)d_in[17];
    const float* rel_b2  = (const float*)d_in[18];
    const float* ln_g    = (const float*)d_in[19];
    const float* ln_b    = (const float*)d_in[20];
    const float* wq      = (const float*)d_in[21];
    const float* wk      = (const float*)d_in[22];
    const float* wv      = (const float*)d_in[23];
    const float* wo      = (const float*)d_in[24];
    const float* wob     = (const float*)d_in[25];
    const float* fw1     = (const float*)d_in[26];
    const float* fb1     = (const float*)d_in[27];
    const float* fa      = (const float*)d_in[28];
    const float* fw2     = (const float*)d_in[29];
    const float* fb2     = (const float*)d_in[30];
    const float* dw1     = (const float*)d_in[31];
    const float* db1     = (const float*)d_in[32];
    const float* da      = (const float*)d_in[33];
    const float* dw2     = (const float*)d_in[34];
    const float* db2     = (const float*)d_in[35];
    float* out = (float*)d_out;

    // ---- workspace layout (bytes), total ~88.6 MB ----
    char* p = (char*)d_ws;
    const size_t SZ_TD  = (size_t)NTOK * DMODEL;      // 2M elems
    float* h = (float*)p;                 p += SZ_TD * 4;
    unsigned short* hnh = (unsigned short*)p; p += SZ_TD * 2;
    unsigned short* hnl = (unsigned short*)p; p += SZ_TD * 2;
    unsigned short* qhg = (unsigned short*)p; p += SZ_TD * 2;
    unsigned short* qmg = (unsigned short*)p; p += SZ_TD * 2;
    unsigned short* kg  = (unsigned short*)p; p += SZ_TD * 2;
    unsigned short* vhg = (unsigned short*)p; p += SZ_TD * 2;   // V^T hi planes
    unsigned short* vlg = (unsigned short*)p; p += SZ_TD * 2;   // V^T lo planes
    unsigned short* obh = (unsigned short*)p; p += SZ_TD * 2;
    unsigned short* obl = (unsigned short*)p; p += SZ_TD * 2;
    unsigned short* midh = (unsigned short*)p; p += (size_t)NTOK * DFF * 2;
    unsigned short* midl = (unsigned short*)p; p += (size_t)NTOK * DFF * 2;
    unsigned short* Ehi = (unsigned short*)p; p += (size_t)2048 * HDIM * 2;   // TILED layout
    unsigned short* Elo = (unsigned short*)p; p += (size_t)2048 * HDIM * 2;   // TILED layout
    float* mk = (float*)p;                p += (size_t)NTOK * 4;
    unsigned short* qkvh = (unsigned short*)p; p += (size_t)1536 * 512 * 2;
    unsigned short* qkvl = (unsigned short*)p; p += (size_t)1536 * 512 * 2;
    unsigned short* woh  = (unsigned short*)p; p += (size_t)512 * 512 * 2;
    unsigned short* wol  = (unsigned short*)p; p += (size_t)512 * 512 * 2;
    unsigned short* f1h  = (unsigned short*)p; p += (size_t)2048 * 512 * 2;
    unsigned short* f1l  = (unsigned short*)p; p += (size_t)2048 * 512 * 2;
    unsigned short* f2h  = (unsigned short*)p; p += (size_t)512 * 2048 * 2;
    unsigned short* f2l  = (unsigned short*)p; p += (size_t)512 * 2048 * 2;
    float* pe = (float*)obh;   // 8 MB spanning obh+obl (free during encode)
    // split-K attention scratch (aliases buffers dead during attention)
    float* Opart = (float*)midh;
    float* Mpart = (float*)hnh;
    float* Lpart = Mpart + (size_t)SPLITK * BB * NHEAD * TT;

    const dim3 blk256(256), blk64(64), blk512(512);
    const dim3 gN512(8, 64);     // 64^2-tile, N=512 shapes (512 blocks)
    const dim3 gN256(4, 64);     // 64^2-tile, dec2
    const dim3 gBQKV(12, 32);    // 128^2-tile, QKV (384 blocks)
    const dim3 gBFFN1(16, 32);   // 128^2-tile, FFN1 (512 blocks = 2/CU capacity)
    #define NP nullptr

    e_kernel<<<dim3(2048), blk64, 0, stream>>>(rel_w1, rel_b1, rel_a, rel_w2, rel_b2, Ehi, Elo);
    mask_kernel<<<dim3(NTOK), blk64, 0, stream>>>(mask_in, mk);
    wcvt<<<dim3(8, 8), blk256, 0, stream>>>(kf_w2, woh, wol, 512, 512);
    wcvt<<<dim3(8, 16), blk256, 0, stream>>>(enc_w1, f1h, f1l, 512, 1024);
    wcvt<<<dim3(8, 8), blk256, 0, stream>>>(enc_w2, qkvh, qkvl, 512, 512);
    kf1_kernel<<<dim3(NTOK*DMODEL/256), blk256, 0, stream>>>(p_kf, kf_w1, kf_b1, kf_a, qhg, qmg);
    gemm_l<<<gN512, blk256, 0, stream>>>(qhg, qmg, woh, wol, kf_b2, NP, NP, pe,
                                         NP, NP, NP, NP, NP, DMODEL, DMODEL, MODE_F32);
    cvt_cat<<<dim3(NTOK*1024/1024), blk256, 0, stream>>>(x, mask_in, midh, midl);
    gemm_l<<<gN512, blk256, 0, stream>>>(midh, midl, f1h, f1l, enc_b1, enc_a1, NP, NP,
                                         hnh, hnl, NP, NP, NP, DMODEL, 2*DMODEL, MODE_BF);
    gemm_l<<<gN512, blk256, 0, stream>>>(hnh, hnl, qkvh, qkvl, enc_b2, enc_a2, pe, h,
                                         NP, NP, NP, NP, NP, DMODEL, DMODEL, MODE_F32);

    for (int i = 0; i < NLAYER; i++) {
        const size_t wofs = (size_t)i * DMODEL * DMODEL;
        wcvt<<<dim3(8, 8), blk256, 0, stream>>>(wq + wofs, qkvh, qkvl, 512, 512);
        wcvt<<<dim3(8, 8), blk256, 0, stream>>>(wk + wofs, qkvh + 512*512, qkvl + 512*512, 512, 512);
        wcvt<<<dim3(8, 8), blk256, 0, stream>>>(wv + wofs, qkvh + 1024*512, qkvl + 1024*512, 512, 512);
        wcvt<<<dim3(8, 8), blk256, 0, stream>>>(wo + wofs, woh, wol, 512, 512);
        wcvt<<<dim3(32, 8), blk256, 0, stream>>>(fw1 + (size_t)i*DMODEL*DFF, f1h, f1l, 2048, 512);
        wcvt<<<dim3(8, 32), blk256, 0, stream>>>(fw2 + (size_t)i*DFF*DMODEL, f2h, f2l, 512, 2048);

        ln_kernel<<<dim3(NTOK), blk64, 0, stream>>>(h, ln_g, ln_b, hnh, hnl);
        gemm_l2<<<gBQKV, blk256, 0, stream>>>(hnh, hnl, qkvh, qkvl, NP, NP, NP, NP,
                                              qhg, qmg, kg, vhg, vlg, 1536, DMODEL, MODE_QKV);
        attn_mfma<<<dim3((TT/128)*SPLITK, NHEAD, BB), blk512, 0, stream>>>(
            (const _Float16*)qhg, (const _Float16*)qmg, (const _Float16*)kg,
            (const _Float16*)vhg, (const _Float16*)vlg,
            (const _Float16*)Ehi, (const _Float16*)Elo, mk, Opart, Mpart, Lpart);
        attn_combine<<<dim3(BB*NHEAD*TT/16), blk256, 0, stream>>>(Opart, Mpart, Lpart, obh, obl);
        gemm_l<<<gN512, blk256, 0, stream>>>(obh, obl, woh, wol, wob + (size_t)i*DMODEL,
                                             NP, h, h, NP, NP, NP, NP, NP, DMODEL, DMODEL, MODE_F32);
        ln_kernel<<<dim3(NTOK), blk64, 0, stream>>>(h, ln_g, ln_b, hnh, hnl);
        gemm_l2<<<gBFFN1, blk256, 0, stream>>>(hnh, hnl, f1h, f1l, fb1 + (size_t)i*DFF, fa + i,
                                               NP, NP, midh, midl, NP, NP, NP, DFF, DMODEL, MODE_BF);
        gemm_l<<<gN512, blk256, 0, stream>>>(midh, midl, f2h, f2l, fb2 + (size_t)i*DMODEL,
                                             NP, h, h, NP, NP, NP, NP, NP, DMODEL, DFF, MODE_F32);
    }
    wcvt<<<dim3(8, 8), blk256, 0, stream>>>(dw1, woh, wol, 512, 512);
    wcvt<<<dim3(4, 8), blk256, 0, stream>>>(dw2, f2h, f2l, 256, 512);
    cvt_pair<<<dim3(SZ_TD/1024), blk256, 0, stream>>>(h, hnh, hnl);
    gemm_l<<<gN512, blk256, 0, stream>>>(hnh, hnl, woh, wol, db1, da, NP, NP,
                                         midh, midl, NP, NP, NP, DMODEL, DMODEL, MODE_BF);
    gemm_l<<<gN256, blk256, 0, stream>>>(midh, midl, f2h, f2l, db2, NP, NP, out,
                                         NP, NP, NP, NP, NP, MFOUT, DMODEL, MODE_F32);
    #undef NP
}

// Round 13
// 1745.358 us; speedup vs baseline: 1.5272x; 1.5272x over previous
//
#include <hip/hip_runtime.h>
#include <cstddef>

#define BB 4
#define TT 1024
#define DMODEL 512
#define DFF 2048
#define NHEAD 8
#define HDIM 64
#define NTOK (BB*TT)
#define NLAYER 6
#define MFOUT 256
#define LDS_STRIDE 72
#define SPLITK 2   // attention K-split: 2 chunks of 8 k-tiles -> 512 blocks = 1 full residency round

typedef __attribute__((ext_vector_type(8))) _Float16 f16x8;
typedef __attribute__((ext_vector_type(8))) short bf16x8;
typedef __attribute__((ext_vector_type(4))) float f32x4;
#define MFMAH(a,b,c) __builtin_amdgcn_mfma_f32_16x16x32_f16(a,b,c,0,0,0)
#define MFMAB(a,b,c) __builtin_amdgcn_mfma_f32_16x16x32_bf16(a,b,c,0,0,0)

union F16U { _Float16 h; unsigned short u; };

__device__ __forceinline__ unsigned f2bf(float f) {
    union { float f; unsigned u; } v; v.f = f;
    return (v.u + 0x7FFFu + ((v.u >> 16) & 1u)) >> 16;
}
__device__ __forceinline__ float bf2f(unsigned h) {
    union { unsigned u; float f; } v; v.u = h << 16;
    return v.f;
}
__device__ __forceinline__ unsigned short f16u(float v) {
    F16U t; t.h = (_Float16)v; return t.u;
}

#define MODE_F32  0   // fp32 out (+optional res)
#define MODE_BF   1   // bf16 hi/lo pair
#define MODE_QKV  5   // gn<512: Q(f16 hi+mid*1024); <1024: K(f16); else V TRANSPOSED (f16 hi/lo planes)

// ---------------- weight convert: fp32 [K][N] -> bf16 hi/lo [N][K] ----------------
__global__ __launch_bounds__(256)
void wcvt(const float* __restrict__ W, unsigned short* __restrict__ Wh,
          unsigned short* __restrict__ Wl, int N, int K)
{
    __shared__ unsigned short Hs[64][LDS_STRIDE];
    __shared__ unsigned short Ls[64][LDS_STRIDE];
    const int tid = threadIdx.x;
    const int n0 = blockIdx.x * 64, k0 = blockIdx.y * 64;
    #pragma unroll
    for (int i = 0; i < 4; i++) {
        const int idx = tid + i * 256;
        const int r = idx >> 4, c4 = (idx & 15) * 4;
        const float4 v = *(const float4*)&W[(size_t)(k0 + r) * N + n0 + c4];
        const float va[4] = {v.x, v.y, v.z, v.w};
        #pragma unroll
        for (int j = 0; j < 4; j++) {
            const unsigned h = f2bf(va[j]);
            Hs[c4 + j][r] = (unsigned short)h;
            Ls[c4 + j][r] = (unsigned short)f2bf(va[j] - bf2f(h));
        }
    }
    __syncthreads();
    #pragma unroll
    for (int i = 0; i < 2; i++) {
        const int idx = tid + i * 256;
        const int r = idx >> 3, c8 = (idx & 7) * 8;
        *(uint4*)&Wh[(size_t)(n0 + r) * K + k0 + c8] = *(const uint4*)&Hs[r][c8];
        *(uint4*)&Wl[(size_t)(n0 + r) * K + k0 + c8] = *(const uint4*)&Ls[r][c8];
    }
}

// ------- epilogue shared by GEMM kernel (gmb/gn computed by caller) -------
__device__ __forceinline__ void gemm_epilogue(
    int mode, int gmb, int gn, int N, const float* bias, const float* alpha,
    float alv, const f32x4& a, const float* __restrict__ res, float* __restrict__ outf,
    unsigned short* __restrict__ o1, unsigned short* __restrict__ o2,
    unsigned short* __restrict__ o3, unsigned short* __restrict__ o4,
    unsigned short* __restrict__ o5)
{
    const float bv = bias ? bias[gn] : 0.f;
    float v4[4];
    #pragma unroll
    for (int r = 0; r < 4; r++) {
        float v = a[r] + bv;
        if (alpha) v = (v >= 0.f) ? v : alv * v;
        v4[r] = v;
    }
    if (mode == MODE_F32) {
        #pragma unroll
        for (int r = 0; r < 4; r++) {
            const size_t oix = (size_t)(gmb + r) * N + gn;
            outf[oix] = v4[r] + (res ? res[oix] : 0.f);
        }
    } else if (mode == MODE_BF) {
        #pragma unroll
        for (int r = 0; r < 4; r++) {
            const size_t oix = (size_t)(gmb + r) * N + gn;
            const unsigned h = f2bf(v4[r]);
            o1[oix] = (unsigned short)h;
            o2[oix] = (unsigned short)f2bf(v4[r] - bf2f(h));
        }
    } else { // MODE_QKV
        const int seg = gn >> 9;
        if (seg == 0) {
            #pragma unroll
            for (int r = 0; r < 4; r++) {
                const size_t qix = (size_t)(gmb + r) * 512 + gn;
                F16U t; t.h = (_Float16)v4[r];
                o1[qix] = t.u;
                o2[qix] = f16u((v4[r] - (float)t.h) * 1024.f);
            }
        } else if (seg == 1) {
            #pragma unroll
            for (int r = 0; r < 4; r++)
                o3[(size_t)(gmb + r) * 512 + (gn - 512)] = f16u(v4[r]);
        } else {
            // V transposed: planes [(bb*8+h)*64 + d][t], 4 consecutive t -> 8B store
            const int d512 = gn - 1024;
            const int bbp = gmb >> 10, t0 = gmb & 1023;
            const size_t vix = ((size_t)(bbp * 8 + (d512 >> 6)) * 64 + (d512 & 63)) * 1024 + t0;
            ushort4 hv, lv;
            unsigned short* hp = (unsigned short*)&hv;
            unsigned short* lp = (unsigned short*)&lv;
            #pragma unroll
            for (int r = 0; r < 4; r++) {
                F16U t; t.h = (_Float16)v4[r];
                hp[r] = t.u;
                lp[r] = f16u(v4[r] - (float)t.h);
            }
            *(ushort4*)&o4[vix] = hv;
            *(ushort4*)&o5[vix] = lv;
        }
    }
}

// ---------------- 64x64-tile pair GEMM (all shapes; R8-verified config) ----------
__global__ __launch_bounds__(256)
void gemm_l(const unsigned short* __restrict__ Ah, const unsigned short* __restrict__ Al,
            const unsigned short* __restrict__ Wh, const unsigned short* __restrict__ Wl,
            const float* __restrict__ bias, const float* __restrict__ alpha,
            const float* __restrict__ res, float* __restrict__ outf,
            unsigned short* __restrict__ o1, unsigned short* __restrict__ o2,
            unsigned short* __restrict__ o3, unsigned short* __restrict__ o4,
            unsigned short* __restrict__ o5, int N, int K, int mode)
{
    __shared__ __align__(16) unsigned short Ahs[64*LDS_STRIDE];
    __shared__ __align__(16) unsigned short Als[64*LDS_STRIDE];
    __shared__ __align__(16) unsigned short Whs[64*LDS_STRIDE];
    __shared__ __align__(16) unsigned short Wls[64*LDS_STRIDE];
    const int tid = threadIdx.x;
    const int lane = tid & 63, w = tid >> 6;
    const int wm = w >> 1, wn = w & 1;
    const int quad = lane >> 4, c = lane & 15;
    const int m0 = blockIdx.y * 64, n0 = blockIdx.x * 64;
    const int sr = tid >> 2, sc = (tid & 3) * 16;

    f32x4 acc[2][2];
    #pragma unroll
    for (int mi = 0; mi < 2; mi++)
        #pragma unroll
        for (int ni = 0; ni < 2; ni++) { acc[mi][ni][0]=0.f; acc[mi][ni][1]=0.f; acc[mi][ni][2]=0.f; acc[mi][ni][3]=0.f; }

    for (int k0 = 0; k0 < K; k0 += 64) {
        const size_t ga = (size_t)(m0 + sr) * K + k0 + sc;
        const size_t gb = (size_t)(n0 + sr) * K + k0 + sc;
        const int ls = sr * LDS_STRIDE + sc;
        *(uint4*)&Ahs[ls]     = *(const uint4*)&Ah[ga];
        *(uint4*)&Ahs[ls + 8] = *(const uint4*)&Ah[ga + 8];
        *(uint4*)&Als[ls]     = *(const uint4*)&Al[ga];
        *(uint4*)&Als[ls + 8] = *(const uint4*)&Al[ga + 8];
        *(uint4*)&Whs[ls]     = *(const uint4*)&Wh[gb];
        *(uint4*)&Whs[ls + 8] = *(const uint4*)&Wh[gb + 8];
        *(uint4*)&Wls[ls]     = *(const uint4*)&Wl[gb];
        *(uint4*)&Wls[ls + 8] = *(const uint4*)&Wl[gb + 8];
        __syncthreads();
        #pragma unroll
        for (int s = 0; s < 2; s++) {
            const int ao = (wm * 32 + c) * LDS_STRIDE + s * 32 + quad * 8;
            const int bo = (wn * 32 + c) * LDS_STRIDE + s * 32 + quad * 8;
            const bf16x8 ah0 = *(const bf16x8*)&Ahs[ao];
            const bf16x8 ah1 = *(const bf16x8*)&Ahs[ao + 16 * LDS_STRIDE];
            const bf16x8 al0 = *(const bf16x8*)&Als[ao];
            const bf16x8 al1 = *(const bf16x8*)&Als[ao + 16 * LDS_STRIDE];
            const bf16x8 bh0 = *(const bf16x8*)&Whs[bo];
            const bf16x8 bh1 = *(const bf16x8*)&Whs[bo + 16 * LDS_STRIDE];
            const bf16x8 bl0 = *(const bf16x8*)&Wls[bo];
            const bf16x8 bl1 = *(const bf16x8*)&Wls[bo + 16 * LDS_STRIDE];
            acc[0][0] = MFMAB(ah0, bh0, acc[0][0]);
            acc[0][1] = MFMAB(ah0, bh1, acc[0][1]);
            acc[1][0] = MFMAB(ah1, bh0, acc[1][0]);
            acc[1][1] = MFMAB(ah1, bh1, acc[1][1]);
            acc[0][0] = MFMAB(al0, bh0, acc[0][0]);
            acc[0][1] = MFMAB(al0, bh1, acc[0][1]);
            acc[1][0] = MFMAB(al1, bh0, acc[1][0]);
            acc[1][1] = MFMAB(al1, bh1, acc[1][1]);
            acc[0][0] = MFMAB(ah0, bl0, acc[0][0]);
            acc[0][1] = MFMAB(ah0, bl1, acc[0][1]);
            acc[1][0] = MFMAB(ah1, bl0, acc[1][0]);
            acc[1][1] = MFMAB(ah1, bl1, acc[1][1]);
        }
        __syncthreads();
    }
    const float alv = alpha ? alpha[0] : 0.f;
    #pragma unroll
    for (int mi = 0; mi < 2; mi++)
        #pragma unroll
        for (int ni = 0; ni < 2; ni++) {
            const int gn = n0 + wn * 32 + ni * 16 + c;
            const int gmb = m0 + wm * 32 + mi * 16 + quad * 4;
            gemm_epilogue(mode, gmb, gn, N, bias, alpha, alv, acc[mi][ni],
                          res, outf, o1, o2, o3, o4, o5);
        }
}

// ---------------- LayerNorm: one wave per token -> bf16 hi/lo pair ----------------
__global__ __launch_bounds__(64)
void ln_kernel(const float* __restrict__ x, const float* __restrict__ g,
               const float* __restrict__ b, unsigned short* __restrict__ oh,
               unsigned short* __restrict__ ol)
{
    const int token = blockIdx.x;
    const int lane = threadIdx.x;
    const float* row = x + (size_t)token * DMODEL;
    float v[8];
    *(float4*)&v[0] = *(const float4*)&row[lane * 4];
    *(float4*)&v[4] = *(const float4*)&row[256 + lane * 4];
    float s = 0.f, s2 = 0.f;
    #pragma unroll
    for (int i = 0; i < 8; i++) { s += v[i]; s2 += v[i] * v[i]; }
    #pragma unroll
    for (int off = 1; off < 64; off <<= 1) {
        s  += __shfl_xor(s, off);
        s2 += __shfl_xor(s2, off);
    }
    const float mean = s * (1.f / DMODEL);
    const float var  = s2 * (1.f / DMODEL) - mean * mean;
    const float rstd = rsqrtf(var + 1e-5f);
    #pragma unroll
    for (int hh = 0; hh < 2; hh++) {
        const int base = hh * 256 + lane * 4;
        const float4 gv = *(const float4*)&g[base];
        const float4 bv = *(const float4*)&b[base];
        float o[4];
        o[0] = (v[hh*4+0] - mean) * rstd * gv.x + bv.x;
        o[1] = (v[hh*4+1] - mean) * rstd * gv.y + bv.y;
        o[2] = (v[hh*4+2] - mean) * rstd * gv.z + bv.z;
        o[3] = (v[hh*4+3] - mean) * rstd * gv.w + bv.w;
        ushort4 ph, pl;
        unsigned short* php = (unsigned short*)&ph;
        unsigned short* plp = (unsigned short*)&pl;
        #pragma unroll
        for (int j = 0; j < 4; j++) {
            const unsigned hb = f2bf(o[j]);
            php[j] = (unsigned short)hb;
            plp[j] = (unsigned short)f2bf(o[j] - bf2f(hb));
        }
        *(ushort4*)&oh[(size_t)token * DMODEL + base] = ph;
        *(ushort4*)&ol[(size_t)token * DMODEL + base] = pl;
    }
}

// ---------------- fp32 -> bf16 hi/lo pair (elementwise) ----------------
__global__ __launch_bounds__(256)
void cvt_pair(const float* __restrict__ x, unsigned short* __restrict__ oh,
              unsigned short* __restrict__ ol)
{
    const int idx = (blockIdx.x * 256 + threadIdx.x) * 4;
    const float4 v = *(const float4*)&x[idx];
    const float va[4] = {v.x, v.y, v.z, v.w};
    ushort4 ph, pl;
    unsigned short* php = (unsigned short*)&ph;
    unsigned short* plp = (unsigned short*)&pl;
    #pragma unroll
    for (int j = 0; j < 4; j++) {
        const unsigned hb = f2bf(va[j]);
        php[j] = (unsigned short)hb;
        plp[j] = (unsigned short)f2bf(va[j] - bf2f(hb));
    }
    *(ushort4*)&oh[idx] = ph;
    *(ushort4*)&ol[idx] = pl;
}

// ---------------- concat [x | mask] -> bf16 pair, [4096][1024] ----------------
__global__ __launch_bounds__(256)
void cvt_cat(const float* __restrict__ x, const float* __restrict__ mask,
             unsigned short* __restrict__ oh, unsigned short* __restrict__ ol)
{
    const int idx = (blockIdx.x * 256 + threadIdx.x) * 4;
    const int row = idx >> 10, col = idx & 1023;
    const float* src = (col < 512) ? &x[(size_t)row * 512 + col]
                                   : &mask[(size_t)row * 512 + col - 512];
    const float4 v = *(const float4*)src;
    const float va[4] = {v.x, v.y, v.z, v.w};
    ushort4 ph, pl;
    unsigned short* php = (unsigned short*)&ph;
    unsigned short* plp = (unsigned short*)&pl;
    #pragma unroll
    for (int j = 0; j < 4; j++) {
        const unsigned hb = f2bf(va[j]);
        php[j] = (unsigned short)hb;
        plp[j] = (unsigned short)f2bf(va[j] - bf2f(hb));
    }
    *(ushort4*)&oh[idx] = ph;
    *(ushort4*)&ol[idx] = pl;
}

// ---------------- attention key-validity mask ----------------
__global__ __launch_bounds__(64)
void mask_kernel(const float* __restrict__ mask_in, float* __restrict__ mk)
{
    const int token = blockIdx.x;
    const int lane = threadIdx.x;
    const float* row = mask_in + (size_t)token * DMODEL;
    const float4 a = *(const float4*)&row[lane * 4];
    const float4 c = *(const float4*)&row[256 + lane * 4];
    float s = a.x + a.y + a.z + a.w + c.x + c.y + c.z + c.w;
    #pragma unroll
    for (int off = 1; off < 64; off <<= 1) s += __shfl_xor(s, off);
    if (lane == 0) mk[token] = (s > 0.f) ? 0.f : -1e9f;
}

// ---------------- relative position table E -> TILED f16 hi/lo ----------------
// Tiled layout for coalesced wave-loads in attn: for 16-row block g and s in {0,1},
//   Et[((g*2+s)*64 + l)*8 + j] = E[16*g + (l&15)][(l>>4)*8 + s*32 + j]
// so a wave (lane=l) fragment load is 1024B CONTIGUOUS. 2048 rows; row 2047
// duplicates row 2046 so the attn index gr in [0,2047] needs no clamp.
__global__ __launch_bounds__(64)
void e_kernel(const float* __restrict__ w1, const float* __restrict__ b1,
              const float* __restrict__ a1, const float* __restrict__ w2,
              const float* __restrict__ b2,
              unsigned short* __restrict__ Ehi, unsigned short* __restrict__ Elo)
{
    __shared__ float t1[DMODEL];
    const int r = blockIdx.x;              // 0..2047
    const int rr = (r > 2046) ? 2046 : r;  // row 2047 = copy of 2046
    const int lane = threadIdx.x;          // col 0..63
    const float rel = (float)rr - 1023.f;
    const float al = a1[0];
    for (int j = lane; j < DMODEL; j += 64) {
        float v = rel * w1[j] + b1[j];
        t1[j] = (v >= 0.f) ? v : al * v;
    }
    __syncthreads();
    float acc = b2[lane];
    for (int j = 0; j < DMODEL; j++)
        acc = fmaf(t1[j], w2[j * HDIM + lane], acc);
    // tiled address for (row=r, col=lane)
    const int g = r >> 4, s = lane >> 5;
    const int l = (((lane >> 3) & 3) << 4) | (r & 15);
    const int j = lane & 7;
    const size_t adr = ((size_t)(g * 2 + s) * 64 + l) * 8 + j;
    F16U t; t.h = (_Float16)acc;
    Ehi[adr] = t.u;
    Elo[adr] = f16u(acc - (float)t.h);
}

// ---------------- keyframe encoder layer 1 (K=2) -> bf16 pair ----------------
__global__ __launch_bounds__(256)
void kf1_kernel(const float* __restrict__ p, const float* __restrict__ w1,
                const float* __restrict__ b1, const float* __restrict__ a1,
                unsigned short* __restrict__ oh, unsigned short* __restrict__ ol)
{
    const int idx = blockIdx.x * 256 + threadIdx.x;
    const int m = idx >> 9, n = idx & 511;
    float v = fmaf(p[m*2], w1[n], fmaf(p[m*2+1], w1[DMODEL + n], b1[n]));
    v = (v >= 0.f) ? v : a1[0] * v;
    const unsigned hb = f2bf(v);
    oh[idx] = (unsigned short)hb;
    ol[idx] = (unsigned short)f2bf(v - bf2f(hb));
}

// ---------------- MFMA flash attention: 128-row Q-block, 8 waves, split-K -------
// R8-verified structure (85us, spill-free, 2-chunk rel-term). R13 change: SPLITK
// 4->2 -> grid 512 blocks = exactly one 2-blocks/CU residency round (vs 2 rounds
// of 1024), Q-load/prologue amortized over 8 tiles, partial-O traffic halved.
__global__ __launch_bounds__(512, 2)
void attn_mfma(const _Float16* __restrict__ qhg, const _Float16* __restrict__ qmg,
               const _Float16* __restrict__ kg, const _Float16* __restrict__ vth,
               const _Float16* __restrict__ vtl, const _Float16* __restrict__ Ehi,
               const _Float16* __restrict__ Elo, const float* __restrict__ mk,
               float* __restrict__ Opart, float* __restrict__ Mpart,
               float* __restrict__ Lpart)
{
    __shared__ __align__(16) _Float16 Ks [64*LDS_STRIDE];
    __shared__ __align__(16) _Float16 Vhs[64*LDS_STRIDE];
    __shared__ __align__(16) _Float16 Vls[64*LDS_STRIDE];
    __shared__ __align__(16) _Float16 Phs[128*LDS_STRIDE];
    __shared__ __align__(16) _Float16 Pls[128*LDS_STRIDE];

    const int tid = threadIdx.x;
    const int lane = tid & 63;
    const int w = tid >> 6;                 // 0..7
    const int quad = lane >> 4;
    const int c = lane & 15;
    const int q0 = (blockIdx.x >> 1) * 128; // 128-row q-block (SPLITK=2)
    const int split = blockIdx.x & 1;
    const int hh = blockIdx.y;
    const int bb = blockIdx.z;
    const size_t base = (size_t)bb * TT * DMODEL + (size_t)hh * HDIM;
    const size_t vbase = (size_t)(bb * NHEAD + hh) * HDIM * TT;
    const float* mkp = mk + bb * TT;
    const int srow = tid >> 3;              // staging: 8 threads/row, 64 rows
    const int scol = (tid & 7) * 8;         // 16B each, 128B contiguous per row

    f16x8 qh[2], qm[2];
    {
        const size_t qrow = base + (size_t)(q0 + 16 * w + c) * DMODEL;
        #pragma unroll
        for (int s = 0; s < 2; s++) {
            qh[s] = *(const f16x8*)&qhg[qrow + s * 32 + quad * 8];
            qm[s] = *(const f16x8*)&qmg[qrow + s * 32 + quad * 8];
        }
    }

    f32x4 O[4];
    #pragma unroll
    for (int dt = 0; dt < 4; dt++) { O[dt][0]=0.f; O[dt][1]=0.f; O[dt][2]=0.f; O[dt][3]=0.f; }
    float mrun[4] = {-1e30f, -1e30f, -1e30f, -1e30f};
    float lrun[4] = {0.f, 0.f, 0.f, 0.f};
    const int Jb = 48 - 16 * w;             // negative for w>=4; gr stays >= 0

    const int ktlo = split * (16 / SPLITK);
    // prefetch tile ktlo staging into registers (small: 3x16B/thread, R7-proven)
    f16x8 sk, svh, svl;
    {
        const int k0 = ktlo * 64;
        sk  = *(const f16x8*)&kg [base + (size_t)(k0 + srow) * DMODEL + scol];
        svh = *(const f16x8*)&vth[vbase + (size_t)srow * TT + k0 + scol];
        svl = *(const f16x8*)&vtl[vbase + (size_t)srow * TT + k0 + scol];
    }
    for (int kt = ktlo; kt < ktlo + (16 / SPLITK); kt++) {
        const int k0 = kt * 64;
        const int rbase = k0 - q0 + 960;

        // write staged tile, then prefetch next tile's regs (flies under compute)
        *(f16x8*)&Ks [srow * LDS_STRIDE + scol] = sk;
        *(f16x8*)&Vhs[srow * LDS_STRIDE + scol] = svh;
        *(f16x8*)&Vls[srow * LDS_STRIDE + scol] = svl;
        __syncthreads();
        {
            const int kn = (kt + 1 < 16) ? (kt + 1) : kt;  // clamp: last prefetch unused
            const int k0n = kn * 64;
            sk  = *(const f16x8*)&kg [base + (size_t)(k0n + srow) * DMODEL + scol];
            svh = *(const f16x8*)&vth[vbase + (size_t)srow * TT + k0n + scol];
            svl = *(const f16x8*)&vtl[vbase + (size_t)srow * TT + k0n + scol];
        }

        // S = Q K^T (K fragments from LDS)
        f32x4 S[4];
        #pragma unroll
        for (int t = 0; t < 4; t++) { S[t][0]=0.f; S[t][1]=0.f; S[t][2]=0.f; S[t][3]=0.f; }
        #pragma unroll
        for (int t = 0; t < 4; t++) {
            const int ko = (16 * t + c) * LDS_STRIDE + quad * 8;
            #pragma unroll
            for (int s = 0; s < 2; s++) {
                const f16x8 kf = *(const f16x8*)&Ks[ko + s * 32];
                S[t] = MFMAH(qh[s], kf, S[t]);
            }
        }
        // rel term from TILED E, in two chunks (3u + 2u) to cap reg pressure.
        float bp[4][5];
        #pragma unroll
        for (int ch = 0; ch < 2; ch++) {
            const int u0 = ch * 3;
            const int nu = ch ? 2 : 3;
            f32x4 R[3], R2[3];
            #pragma unroll
            for (int v = 0; v < 3; v++) {
                if (v >= nu) continue;
                R[v][0]=0.f; R[v][1]=0.f; R[v][2]=0.f; R[v][3]=0.f;
                R2[v][0]=0.f; R2[v][1]=0.f; R2[v][2]=0.f; R2[v][3]=0.f;
            }
            #pragma unroll
            for (int v = 0; v < 3; v++) {
                if (v >= nu) continue;
                const int g = (rbase + Jb + 16 * (u0 + v)) >> 4;
                const size_t eb0 = ((size_t)(g * 2 + 0) * 64 + lane) * 8;
                const size_t eb1 = ((size_t)(g * 2 + 1) * 64 + lane) * 8;
                const f16x8 eh0 = *(const f16x8*)&Ehi[eb0];
                const f16x8 eh1 = *(const f16x8*)&Ehi[eb1];
                const f16x8 el0 = *(const f16x8*)&Elo[eb0];
                const f16x8 el1 = *(const f16x8*)&Elo[eb1];
                R[v]  = MFMAH(qh[0], eh0, R[v]);
                R[v]  = MFMAH(qh[1], eh1, R[v]);
                R[v]  = MFMAH(qh[0], el0, R[v]);
                R[v]  = MFMAH(qh[1], el1, R[v]);
                R2[v] = MFMAH(qm[0], eh0, R2[v]);
                R2[v] = MFMAH(qm[1], eh1, R2[v]);
            }
            #pragma unroll
            for (int v = 0; v < 3; v++) {
                if (v >= nu) continue;
                #pragma unroll
                for (int r = 0; r < 4; r++) {
                    const float rv = fmaf(R2[v][r], 9.765625e-4f, R[v][r]);
                    const int q = quad * 4 + r;
                    const int srcl = (quad << 4) | ((c - q + 15) & 15);
                    bp[r][u0 + v] = __int_as_float(__builtin_amdgcn_ds_bpermute(srcl << 2, __float_as_int(rv)));
                }
            }
        }
        float mkv[4];
        #pragma unroll
        for (int t = 0; t < 4; t++) mkv[t] = mkp[k0 + 16*t + c];
        float tmax[4] = {-3e38f, -3e38f, -3e38f, -3e38f};
        #pragma unroll
        for (int t = 0; t < 4; t++)
            #pragma unroll
            for (int r = 0; r < 4; r++) {
                const int q = quad*4 + r;
                const int jj = 16*t + c - q + 15;
                const float rv = ((jj >> 4) == t) ? bp[r][t] : bp[r][t+1];
                const float v = (S[t][r] + rv) * 0.125f + mkv[t];
                S[t][r] = v;
                tmax[r] = fmaxf(tmax[r], v);
            }
        #pragma unroll
        for (int r = 0; r < 4; r++) {
            tmax[r] = fmaxf(tmax[r], __shfl_xor(tmax[r], 1));
            tmax[r] = fmaxf(tmax[r], __shfl_xor(tmax[r], 2));
            tmax[r] = fmaxf(tmax[r], __shfl_xor(tmax[r], 4));
            tmax[r] = fmaxf(tmax[r], __shfl_xor(tmax[r], 8));
        }
        float corr[4];
        #pragma unroll
        for (int r = 0; r < 4; r++) {
            const float mn = fmaxf(mrun[r], tmax[r]);
            corr[r] = __expf(mrun[r] - mn);
            mrun[r] = mn;
            lrun[r] *= corr[r];
        }
        #pragma unroll
        for (int dt = 0; dt < 4; dt++)
            #pragma unroll
            for (int r = 0; r < 4; r++) O[dt][r] *= corr[r];
        float psum[4] = {0.f, 0.f, 0.f, 0.f};
        #pragma unroll
        for (int t = 0; t < 4; t++)
            #pragma unroll
            for (int r = 0; r < 4; r++) {
                const float p = __expf(S[t][r] - mrun[r]);
                psum[r] += p;
                const _Float16 hp = (_Float16)p;
                Phs[(w*16 + quad*4 + r)*LDS_STRIDE + 16*t + c] = hp;
                Pls[(w*16 + quad*4 + r)*LDS_STRIDE + 16*t + c] = (_Float16)(p - (float)hp);
            }
        #pragma unroll
        for (int r = 0; r < 4; r++) {
            psum[r] += __shfl_xor(psum[r], 1);
            psum[r] += __shfl_xor(psum[r], 2);
            psum[r] += __shfl_xor(psum[r], 4);
            psum[r] += __shfl_xor(psum[r], 8);
            lrun[r] += psum[r];
        }
        // P write -> P read: same-wave DS ordering + compiler-tracked aliasing
        // (fence-free correctness verified R5-R12).
        f16x8 pfh[2], pfl[2];
        #pragma unroll
        for (int s = 0; s < 2; s++) {
            pfh[s] = *(const f16x8*)&Phs[(w*16 + c)*LDS_STRIDE + s*32 + quad*8];
            pfl[s] = *(const f16x8*)&Pls[(w*16 + c)*LDS_STRIDE + s*32 + quad*8];
        }
        // O += P V (V fragments from LDS)
        #pragma unroll
        for (int dt = 0; dt < 4; dt++) {
            const int vo = (16 * dt + c) * LDS_STRIDE + quad * 8;
            #pragma unroll
            for (int s = 0; s < 2; s++) {
                const f16x8 vhf = *(const f16x8*)&Vhs[vo + s * 32];
                const f16x8 vlf = *(const f16x8*)&Vls[vo + s * 32];
                O[dt] = MFMAH(pfh[s], vhf, O[dt]);
                O[dt] = MFMAH(pfl[s], vhf, O[dt]);
                O[dt] = MFMAH(pfh[s], vlf, O[dt]);
            }
        }
        __syncthreads();   // all waves done with Ks/Vhs/Vls before next overwrite
    }
    // write partial: unnormalized O (f32) + m,l per q-row
    const size_t obase = (size_t)((split * BB + bb) * NHEAD + hh) * TT + q0 + 16 * w;
    #pragma unroll
    for (int r = 0; r < 4; r++) {
        if (c == 0) {
            Mpart[obase + quad * 4 + r] = mrun[r];
            Lpart[obase + quad * 4 + r] = lrun[r];
        }
    }
    #pragma unroll
    for (int dt = 0; dt < 4; dt++)
        #pragma unroll
        for (int r = 0; r < 4; r++)
            Opart[(obase + quad * 4 + r) * HDIM + 16 * dt + c] = O[dt][r];
}

// ---------------- combine SPLITK attention partials -> bf16 hi/lo ----------------
__global__ __launch_bounds__(256)
void attn_combine(const float* __restrict__ Opart, const float* __restrict__ Mpart,
                  const float* __restrict__ Lpart,
                  unsigned short* __restrict__ obh, unsigned short* __restrict__ obl)
{
    const int tid = threadIdx.x;
    const int row = blockIdx.x * 16 + (tid >> 4);   // (bb*H+hh)*T + q
    const int d0 = (tid & 15) * 4;
    const int SR = BB * NHEAD * TT;
    float mv[SPLITK];
    float m = -3e38f;
    #pragma unroll
    for (int i = 0; i < SPLITK; i++) { mv[i] = Mpart[i * SR + row]; m = fmaxf(m, mv[i]); }
    float wv[SPLITK];
    float l = 0.f;
    #pragma unroll
    for (int i = 0; i < SPLITK; i++) {
        wv[i] = __expf(mv[i] - m);
        l += wv[i] * Lpart[i * SR + row];
    }
    const float inv = 1.f / l;
    float o[4] = {0.f, 0.f, 0.f, 0.f};
    #pragma unroll
    for (int i = 0; i < SPLITK; i++) {
        const float4 v = *(const float4*)&Opart[((size_t)i * SR + row) * HDIM + d0];
        o[0] = fmaf(wv[i], v.x, o[0]);
        o[1] = fmaf(wv[i], v.y, o[1]);
        o[2] = fmaf(wv[i], v.z, o[2]);
        o[3] = fmaf(wv[i], v.w, o[3]);
    }
    const int q = row & (TT - 1), bh = row >> 10;
    const size_t oix = ((size_t)((bh >> 3) * TT + q)) * DMODEL + (size_t)(bh & 7) * HDIM + d0;
    ushort4 ph, pl;
    unsigned short* php = (unsigned short*)&ph;
    unsigned short* plp = (unsigned short*)&pl;
    #pragma unroll
    for (int j = 0; j < 4; j++) {
        const float v = o[j] * inv;
        const unsigned hb = f2bf(v);
        php[j] = (unsigned short)hb;
        plp[j] = (unsigned short)f2bf(v - bf2f(hb));
    }
    *(ushort4*)&obh[oix] = ph;
    *(ushort4*)&obl[oix] = pl;
}

extern "C" void kernel_launch(void* const* d_in, const int* in_sizes, int n_in,
                              void* d_out, int out_size, void* d_ws, size_t ws_size,
                              hipStream_t stream)
{
    const float* x       = (const float*)d_in[0];
    const float* mask_in = (const float*)d_in[1];
    const float* p_kf    = (const float*)d_in[2];
    const float* enc_w1  = (const float*)d_in[3];
    const float* enc_b1  = (const float*)d_in[4];
    const float* enc_a1  = (const float*)d_in[5];
    const float* enc_w2  = (const float*)d_in[6];
    const float* enc_b2  = (const float*)d_in[7];
    const float* enc_a2  = (const float*)d_in[8];
    const float* kf_w1   = (const float*)d_in[9];
    const float* kf_b1   = (const float*)d_in[10];
    const float* kf_a    = (const float*)d_in[11];
    const float* kf_w2   = (const float*)d_in[12];
    const float* kf_b2   = (const float*)d_in[13];
    const float* rel_w1  = (const float*)d_in[14];
    const float* rel_b1  = (const float*)d_in[15];
    const float* rel_a   = (const float*)d_in[16];
    const float* rel_w2  = (const float*)d_in[17];
    const float* rel_b2  = (const float*)d_in[18];
    const float* ln_g    = (const float*)d_in[19];
    const float* ln_b    = (const float*)d_in[20];
    const float* wq      = (const float*)d_in[21];
    const float* wk      = (const float*)d_in[22];
    const float* wv      = (const float*)d_in[23];
    const float* wo      = (const float*)d_in[24];
    const float* wob     = (const float*)d_in[25];
    const float* fw1     = (const float*)d_in[26];
    const float* fb1     = (const float*)d_in[27];
    const float* fa      = (const float*)d_in[28];
    const float* fw2     = (const float*)d_in[29];
    const float* fb2     = (const float*)d_in[30];
    const float* dw1     = (const float*)d_in[31];
    const float* db1     = (const float*)d_in[32];
    const float* da      = (const float*)d_in[33];
    const float* dw2     = (const float*)d_in[34];
    const float* db2     = (const float*)d_in[35];
    float* out = (float*)d_out;

    // ---- workspace layout (bytes), total ~88.6 MB ----
    char* p = (char*)d_ws;
    const size_t SZ_TD  = (size_t)NTOK * DMODEL;      // 2M elems
    float* h = (float*)p;                 p += SZ_TD * 4;
    unsigned short* hnh = (unsigned short*)p; p += SZ_TD * 2;
    unsigned short* hnl = (unsigned short*)p; p += SZ_TD * 2;
    unsigned short* qhg = (unsigned short*)p; p += SZ_TD * 2;
    unsigned short* qmg = (unsigned short*)p; p += SZ_TD * 2;
    unsigned short* kg  = (unsigned short*)p; p += SZ_TD * 2;
    unsigned short* vhg = (unsigned short*)p; p += SZ_TD * 2;   // V^T hi planes
    unsigned short* vlg = (unsigned short*)p; p += SZ_TD * 2;   // V^T lo planes
    unsigned short* obh = (unsigned short*)p; p += SZ_TD * 2;
    unsigned short* obl = (unsigned short*)p; p += SZ_TD * 2;
    unsigned short* midh = (unsigned short*)p; p += (size_t)NTOK * DFF * 2;
    unsigned short* midl = (unsigned short*)p; p += (size_t)NTOK * DFF * 2;
    unsigned short* Ehi = (unsigned short*)p; p += (size_t)2048 * HDIM * 2;   // TILED layout
    unsigned short* Elo = (unsigned short*)p; p += (size_t)2048 * HDIM * 2;   // TILED layout
    float* mk = (float*)p;                p += (size_t)NTOK * 4;
    unsigned short* qkvh = (unsigned short*)p; p += (size_t)1536 * 512 * 2;
    unsigned short* qkvl = (unsigned short*)p; p += (size_t)1536 * 512 * 2;
    unsigned short* woh  = (unsigned short*)p; p += (size_t)512 * 512 * 2;
    unsigned short* wol  = (unsigned short*)p; p += (size_t)512 * 512 * 2;
    unsigned short* f1h  = (unsigned short*)p; p += (size_t)2048 * 512 * 2;
    unsigned short* f1l  = (unsigned short*)p; p += (size_t)2048 * 512 * 2;
    unsigned short* f2h  = (unsigned short*)p; p += (size_t)512 * 2048 * 2;
    unsigned short* f2l  = (unsigned short*)p; p += (size_t)512 * 2048 * 2;
    float* pe = (float*)obh;   // 8 MB spanning obh+obl (free during encode)
    // split-K attention scratch (aliases buffers dead during attention)
    float* Opart = (float*)midh;
    float* Mpart = (float*)hnh;
    float* Lpart = Mpart + (size_t)SPLITK * BB * NHEAD * TT;

    const dim3 blk256(256), blk64(64), blk512(512);
    const dim3 gN512(8, 64);
    const dim3 gQKV(24, 64);
    const dim3 gFFN1(32, 64);
    const dim3 gN256(4, 64);
    #define NP nullptr

    e_kernel<<<dim3(2048), blk64, 0, stream>>>(rel_w1, rel_b1, rel_a, rel_w2, rel_b2, Ehi, Elo);
    mask_kernel<<<dim3(NTOK), blk64, 0, stream>>>(mask_in, mk);
    wcvt<<<dim3(8, 8), blk256, 0, stream>>>(kf_w2, woh, wol, 512, 512);
    wcvt<<<dim3(8, 16), blk256, 0, stream>>>(enc_w1, f1h, f1l, 512, 1024);
    wcvt<<<dim3(8, 8), blk256, 0, stream>>>(enc_w2, qkvh, qkvl, 512, 512);
    kf1_kernel<<<dim3(NTOK*DMODEL/256), blk256, 0, stream>>>(p_kf, kf_w1, kf_b1, kf_a, qhg, qmg);
    gemm_l<<<gN512, blk256, 0, stream>>>(qhg, qmg, woh, wol, kf_b2, NP, NP, pe,
                                         NP, NP, NP, NP, NP, DMODEL, DMODEL, MODE_F32);
    cvt_cat<<<dim3(NTOK*1024/1024), blk256, 0, stream>>>(x, mask_in, midh, midl);
    gemm_l<<<gN512, blk256, 0, stream>>>(midh, midl, f1h, f1l, enc_b1, enc_a1, NP, NP,
                                         hnh, hnl, NP, NP, NP, DMODEL, 2*DMODEL, MODE_BF);
    gemm_l<<<gN512, blk256, 0, stream>>>(hnh, hnl, qkvh, qkvl, enc_b2, enc_a2, pe, h,
                                         NP, NP, NP, NP, NP, DMODEL, DMODEL, MODE_F32);

    for (int i = 0; i < NLAYER; i++) {
        const size_t wofs = (size_t)i * DMODEL * DMODEL;
        wcvt<<<dim3(8, 8), blk256, 0, stream>>>(wq + wofs, qkvh, qkvl, 512, 512);
        wcvt<<<dim3(8, 8), blk256, 0, stream>>>(wk + wofs, qkvh + 512*512, qkvl + 512*512, 512, 512);
        wcvt<<<dim3(8, 8), blk256, 0, stream>>>(wv + wofs, qkvh + 1024*512, qkvl + 1024*512, 512, 512);
        wcvt<<<dim3(8, 8), blk256, 0, stream>>>(wo + wofs, woh, wol, 512, 512);
        wcvt<<<dim3(32, 8), blk256, 0, stream>>>(fw1 + (size_t)i*DMODEL*DFF, f1h, f1l, 2048, 512);
        wcvt<<<dim3(8, 32), blk256, 0, stream>>>(fw2 + (size_t)i*DFF*DMODEL, f2h, f2l, 512, 2048);

        ln_kernel<<<dim3(NTOK), blk64, 0, stream>>>(h, ln_g, ln_b, hnh, hnl);
        gemm_l<<<gQKV, blk256, 0, stream>>>(hnh, hnl, qkvh, qkvl, NP, NP, NP, NP,
                                            qhg, qmg, kg, vhg, vlg, 1536, DMODEL, MODE_QKV);
        attn_mfma<<<dim3((TT/128)*SPLITK, NHEAD, BB), blk512, 0, stream>>>(
            (const _Float16*)qhg, (const _Float16*)qmg, (const _Float16*)kg,
            (const _Float16*)vhg, (const _Float16*)vlg,
            (const _Float16*)Ehi, (const _Float16*)Elo, mk, Opart, Mpart, Lpart);
        attn_combine<<<dim3(BB*NHEAD*TT/16), blk256, 0, stream>>>(Opart, Mpart, Lpart, obh, obl);
        gemm_l<<<gN512, blk256, 0, stream>>>(obh, obl, woh, wol, wob + (size_t)i*DMODEL,
                                             NP, h, h, NP, NP, NP, NP, NP, DMODEL, DMODEL, MODE_F32);
        ln_kernel<<<dim3(NTOK), blk64, 0, stream>>>(h, ln_g, ln_b, hnh, hnl);
        gemm_l<<<gFFN1, blk256, 0, stream>>>(hnh, hnl, f1h, f1l, fb1 + (size_t)i*DFF, fa + i,
                                             NP, NP, midh, midl, NP, NP, NP, DFF, DMODEL, MODE_BF);
        gemm_l<<<gN512, blk256, 0, stream>>>(midh, midl, f2h, f2l, fb2 + (size_t)i*DMODEL,
                                             NP, h, h, NP, NP, NP, NP, NP, DMODEL, DFF, MODE_F32);
    }
    wcvt<<<dim3(8, 8), blk256, 0, stream>>>(dw1, woh, wol, 512, 512);
    wcvt<<<dim3(4, 8), blk256, 0, stream>>>(dw2, f2h, f2l, 256, 512);
    cvt_pair<<<dim3(SZ_TD/1024), blk256, 0, stream>>>(h, hnh, hnl);
    gemm_l<<<gN512, blk256, 0, stream>>>(hnh, hnl, woh, wol, db1, da, NP, NP,
                                         midh, midl, NP, NP, NP, DMODEL, DMODEL, MODE_BF);
    gemm_l<<<gN256, blk256, 0, stream>>>(midh, midl, f2h, f2l, db2, NP, NP, out,
                                         NP, NP, NP, NP, NP, MFOUT, DMODEL, MODE_F32);
    #undef NP
}

// Round 14
// 1672.780 us; speedup vs baseline: 1.5935x; 1.0434x over previous
//
#include <hip/hip_runtime.h>
#include <cstddef>

#define BB 4
#define TT 1024
#define DMODEL 512
#define DFF 2048
#define NHEAD 8
#define HDIM 64
#define NTOK (BB*TT)
#define NLAYER 6
#define MFOUT 256
#define LDS_STRIDE 72
#define SPLITK 2   // attention K-split: 2 chunks of 8 k-tiles -> 512 blocks = 1 full residency round

typedef __attribute__((ext_vector_type(8))) _Float16 f16x8;
typedef __attribute__((ext_vector_type(8))) short bf16x8;
typedef __attribute__((ext_vector_type(4))) float f32x4;
#define MFMAH(a,b,c) __builtin_amdgcn_mfma_f32_16x16x32_f16(a,b,c,0,0,0)
#define MFMAB(a,b,c) __builtin_amdgcn_mfma_f32_16x16x32_bf16(a,b,c,0,0,0)

union F16U { _Float16 h; unsigned short u; };

__device__ __forceinline__ unsigned f2bf(float f) {
    union { float f; unsigned u; } v; v.f = f;
    return (v.u + 0x7FFFu + ((v.u >> 16) & 1u)) >> 16;
}
__device__ __forceinline__ float bf2f(unsigned h) {
    union { unsigned u; float f; } v; v.u = h << 16;
    return v.f;
}
__device__ __forceinline__ unsigned short f16u(float v) {
    F16U t; t.h = (_Float16)v; return t.u;
}

#define MODE_F32  0   // fp32 out (+optional res)
#define MODE_BF   1   // bf16 hi/lo pair
#define MODE_QKV  5   // gn<512: Q(f16 hi+mid*1024); <1024: K(f16); else V TRANSPOSED (f16 hi/lo planes)

// ---------------- weight convert body: fp32 [K][N] tile -> bf16 hi/lo [N][K] ------
__device__ __forceinline__ void wcvt_body(
    const float* __restrict__ W, unsigned short* __restrict__ Wh,
    unsigned short* __restrict__ Wl, int N, int K, int n0, int k0)
{
    __shared__ unsigned short Hs[64][LDS_STRIDE];
    __shared__ unsigned short Ls[64][LDS_STRIDE];
    const int tid = threadIdx.x;
    #pragma unroll
    for (int i = 0; i < 4; i++) {
        const int idx = tid + i * 256;
        const int r = idx >> 4, c4 = (idx & 15) * 4;
        const float4 v = *(const float4*)&W[(size_t)(k0 + r) * N + n0 + c4];
        const float va[4] = {v.x, v.y, v.z, v.w};
        #pragma unroll
        for (int j = 0; j < 4; j++) {
            const unsigned h = f2bf(va[j]);
            Hs[c4 + j][r] = (unsigned short)h;
            Ls[c4 + j][r] = (unsigned short)f2bf(va[j] - bf2f(h));
        }
    }
    __syncthreads();
    #pragma unroll
    for (int i = 0; i < 2; i++) {
        const int idx = tid + i * 256;
        const int r = idx >> 3, c8 = (idx & 7) * 8;
        *(uint4*)&Wh[(size_t)(n0 + r) * K + k0 + c8] = *(const uint4*)&Hs[r][c8];
        *(uint4*)&Wl[(size_t)(n0 + r) * K + k0 + c8] = *(const uint4*)&Ls[r][c8];
    }
}

// ---------------- single-weight wcvt (encoder/decoder one-time conversions) ------
__global__ __launch_bounds__(256)
void wcvt(const float* __restrict__ W, unsigned short* __restrict__ Wh,
          unsigned short* __restrict__ Wl, int N, int K)
{
    wcvt_body(W, Wh, Wl, N, K, blockIdx.x * 64, blockIdx.y * 64);
}

// ---------------- fused per-layer weight conversion: 6 launches -> 1 -------------
// 768 blocks: [0,192) wq/wk/wv -> qkv(+seg ofs); [192,256) wo; [256,512) fw1
// (32x8 grid); [512,768) fw2 (8x32 grid). Inner body identical to wcvt.
__global__ __launch_bounds__(256)
void wcvt6(const float* __restrict__ Wq, const float* __restrict__ Wk,
           const float* __restrict__ Wv, const float* __restrict__ Wo,
           const float* __restrict__ F1, const float* __restrict__ F2,
           unsigned short* __restrict__ qkvh, unsigned short* __restrict__ qkvl,
           unsigned short* __restrict__ woh, unsigned short* __restrict__ wol,
           unsigned short* __restrict__ f1h, unsigned short* __restrict__ f1l,
           unsigned short* __restrict__ f2h, unsigned short* __restrict__ f2l)
{
    const int b = blockIdx.x;
    if (b < 192) {
        const int which = b >> 6, bb = b & 63;
        const float* W = (which == 0) ? Wq : (which == 1) ? Wk : Wv;
        wcvt_body(W, qkvh + (size_t)which * 512 * 512, qkvl + (size_t)which * 512 * 512,
                  512, 512, (bb & 7) * 64, (bb >> 3) * 64);
    } else if (b < 256) {
        const int bb = b - 192;
        wcvt_body(Wo, woh, wol, 512, 512, (bb & 7) * 64, (bb >> 3) * 64);
    } else if (b < 512) {
        const int bb = b - 256;
        wcvt_body(F1, f1h, f1l, 2048, 512, (bb & 31) * 64, (bb >> 5) * 64);
    } else {
        const int bb = b - 512;
        wcvt_body(F2, f2h, f2l, 512, 2048, (bb & 7) * 64, (bb >> 3) * 64);
    }
}

// ------- epilogue shared by GEMM kernel (gmb/gn computed by caller) -------
__device__ __forceinline__ void gemm_epilogue(
    int mode, int gmb, int gn, int N, const float* bias, const float* alpha,
    float alv, const f32x4& a, const float* __restrict__ res, float* __restrict__ outf,
    unsigned short* __restrict__ o1, unsigned short* __restrict__ o2,
    unsigned short* __restrict__ o3, unsigned short* __restrict__ o4,
    unsigned short* __restrict__ o5)
{
    const float bv = bias ? bias[gn] : 0.f;
    float v4[4];
    #pragma unroll
    for (int r = 0; r < 4; r++) {
        float v = a[r] + bv;
        if (alpha) v = (v >= 0.f) ? v : alv * v;
        v4[r] = v;
    }
    if (mode == MODE_F32) {
        #pragma unroll
        for (int r = 0; r < 4; r++) {
            const size_t oix = (size_t)(gmb + r) * N + gn;
            outf[oix] = v4[r] + (res ? res[oix] : 0.f);
        }
    } else if (mode == MODE_BF) {
        #pragma unroll
        for (int r = 0; r < 4; r++) {
            const size_t oix = (size_t)(gmb + r) * N + gn;
            const unsigned h = f2bf(v4[r]);
            o1[oix] = (unsigned short)h;
            o2[oix] = (unsigned short)f2bf(v4[r] - bf2f(h));
        }
    } else { // MODE_QKV
        const int seg = gn >> 9;
        if (seg == 0) {
            #pragma unroll
            for (int r = 0; r < 4; r++) {
                const size_t qix = (size_t)(gmb + r) * 512 + gn;
                F16U t; t.h = (_Float16)v4[r];
                o1[qix] = t.u;
                o2[qix] = f16u((v4[r] - (float)t.h) * 1024.f);
            }
        } else if (seg == 1) {
            #pragma unroll
            for (int r = 0; r < 4; r++)
                o3[(size_t)(gmb + r) * 512 + (gn - 512)] = f16u(v4[r]);
        } else {
            // V transposed: planes [(bb*8+h)*64 + d][t], 4 consecutive t -> 8B store
            const int d512 = gn - 1024;
            const int bbp = gmb >> 10, t0 = gmb & 1023;
            const size_t vix = ((size_t)(bbp * 8 + (d512 >> 6)) * 64 + (d512 & 63)) * 1024 + t0;
            ushort4 hv, lv;
            unsigned short* hp = (unsigned short*)&hv;
            unsigned short* lp = (unsigned short*)&lv;
            #pragma unroll
            for (int r = 0; r < 4; r++) {
                F16U t; t.h = (_Float16)v4[r];
                hp[r] = t.u;
                lp[r] = f16u(v4[r] - (float)t.h);
            }
            *(ushort4*)&o4[vix] = hv;
            *(ushort4*)&o5[vix] = lv;
        }
    }
}

// ---------------- 64x64-tile pair GEMM (all shapes; R8-verified config) ----------
__global__ __launch_bounds__(256)
void gemm_l(const unsigned short* __restrict__ Ah, const unsigned short* __restrict__ Al,
            const unsigned short* __restrict__ Wh, const unsigned short* __restrict__ Wl,
            const float* __restrict__ bias, const float* __restrict__ alpha,
            const float* __restrict__ res, float* __restrict__ outf,
            unsigned short* __restrict__ o1, unsigned short* __restrict__ o2,
            unsigned short* __restrict__ o3, unsigned short* __restrict__ o4,
            unsigned short* __restrict__ o5, int N, int K, int mode)
{
    __shared__ __align__(16) unsigned short Ahs[64*LDS_STRIDE];
    __shared__ __align__(16) unsigned short Als[64*LDS_STRIDE];
    __shared__ __align__(16) unsigned short Whs[64*LDS_STRIDE];
    __shared__ __align__(16) unsigned short Wls[64*LDS_STRIDE];
    const int tid = threadIdx.x;
    const int lane = tid & 63, w = tid >> 6;
    const int wm = w >> 1, wn = w & 1;
    const int quad = lane >> 4, c = lane & 15;
    const int m0 = blockIdx.y * 64, n0 = blockIdx.x * 64;
    const int sr = tid >> 2, sc = (tid & 3) * 16;

    f32x4 acc[2][2];
    #pragma unroll
    for (int mi = 0; mi < 2; mi++)
        #pragma unroll
        for (int ni = 0; ni < 2; ni++) { acc[mi][ni][0]=0.f; acc[mi][ni][1]=0.f; acc[mi][ni][2]=0.f; acc[mi][ni][3]=0.f; }

    for (int k0 = 0; k0 < K; k0 += 64) {
        const size_t ga = (size_t)(m0 + sr) * K + k0 + sc;
        const size_t gb = (size_t)(n0 + sr) * K + k0 + sc;
        const int ls = sr * LDS_STRIDE + sc;
        *(uint4*)&Ahs[ls]     = *(const uint4*)&Ah[ga];
        *(uint4*)&Ahs[ls + 8] = *(const uint4*)&Ah[ga + 8];
        *(uint4*)&Als[ls]     = *(const uint4*)&Al[ga];
        *(uint4*)&Als[ls + 8] = *(const uint4*)&Al[ga + 8];
        *(uint4*)&Whs[ls]     = *(const uint4*)&Wh[gb];
        *(uint4*)&Whs[ls + 8] = *(const uint4*)&Wh[gb + 8];
        *(uint4*)&Wls[ls]     = *(const uint4*)&Wl[gb];
        *(uint4*)&Wls[ls + 8] = *(const uint4*)&Wl[gb + 8];
        __syncthreads();
        #pragma unroll
        for (int s = 0; s < 2; s++) {
            const int ao = (wm * 32 + c) * LDS_STRIDE + s * 32 + quad * 8;
            const int bo = (wn * 32 + c) * LDS_STRIDE + s * 32 + quad * 8;
            const bf16x8 ah0 = *(const bf16x8*)&Ahs[ao];
            const bf16x8 ah1 = *(const bf16x8*)&Ahs[ao + 16 * LDS_STRIDE];
            const bf16x8 al0 = *(const bf16x8*)&Als[ao];
            const bf16x8 al1 = *(const bf16x8*)&Als[ao + 16 * LDS_STRIDE];
            const bf16x8 bh0 = *(const bf16x8*)&Whs[bo];
            const bf16x8 bh1 = *(const bf16x8*)&Whs[bo + 16 * LDS_STRIDE];
            const bf16x8 bl0 = *(const bf16x8*)&Wls[bo];
            const bf16x8 bl1 = *(const bf16x8*)&Wls[bo + 16 * LDS_STRIDE];
            acc[0][0] = MFMAB(ah0, bh0, acc[0][0]);
            acc[0][1] = MFMAB(ah0, bh1, acc[0][1]);
            acc[1][0] = MFMAB(ah1, bh0, acc[1][0]);
            acc[1][1] = MFMAB(ah1, bh1, acc[1][1]);
            acc[0][0] = MFMAB(al0, bh0, acc[0][0]);
            acc[0][1] = MFMAB(al0, bh1, acc[0][1]);
            acc[1][0] = MFMAB(al1, bh0, acc[1][0]);
            acc[1][1] = MFMAB(al1, bh1, acc[1][1]);
            acc[0][0] = MFMAB(ah0, bl0, acc[0][0]);
            acc[0][1] = MFMAB(ah0, bl1, acc[0][1]);
            acc[1][0] = MFMAB(ah1, bl0, acc[1][0]);
            acc[1][1] = MFMAB(ah1, bl1, acc[1][1]);
        }
        __syncthreads();
    }
    const float alv = alpha ? alpha[0] : 0.f;
    #pragma unroll
    for (int mi = 0; mi < 2; mi++)
        #pragma unroll
        for (int ni = 0; ni < 2; ni++) {
            const int gn = n0 + wn * 32 + ni * 16 + c;
            const int gmb = m0 + wm * 32 + mi * 16 + quad * 4;
            gemm_epilogue(mode, gmb, gn, N, bias, alpha, alv, acc[mi][ni],
                          res, outf, o1, o2, o3, o4, o5);
        }
}

// ---------------- LayerNorm: one wave per token -> bf16 hi/lo pair ----------------
__global__ __launch_bounds__(64)
void ln_kernel(const float* __restrict__ x, const float* __restrict__ g,
               const float* __restrict__ b, unsigned short* __restrict__ oh,
               unsigned short* __restrict__ ol)
{
    const int token = blockIdx.x;
    const int lane = threadIdx.x;
    const float* row = x + (size_t)token * DMODEL;
    float v[8];
    *(float4*)&v[0] = *(const float4*)&row[lane * 4];
    *(float4*)&v[4] = *(const float4*)&row[256 + lane * 4];
    float s = 0.f, s2 = 0.f;
    #pragma unroll
    for (int i = 0; i < 8; i++) { s += v[i]; s2 += v[i] * v[i]; }
    #pragma unroll
    for (int off = 1; off < 64; off <<= 1) {
        s  += __shfl_xor(s, off);
        s2 += __shfl_xor(s2, off);
    }
    const float mean = s * (1.f / DMODEL);
    const float var  = s2 * (1.f / DMODEL) - mean * mean;
    const float rstd = rsqrtf(var + 1e-5f);
    #pragma unroll
    for (int hh = 0; hh < 2; hh++) {
        const int base = hh * 256 + lane * 4;
        const float4 gv = *(const float4*)&g[base];
        const float4 bv = *(const float4*)&b[base];
        float o[4];
        o[0] = (v[hh*4+0] - mean) * rstd * gv.x + bv.x;
        o[1] = (v[hh*4+1] - mean) * rstd * gv.y + bv.y;
        o[2] = (v[hh*4+2] - mean) * rstd * gv.z + bv.z;
        o[3] = (v[hh*4+3] - mean) * rstd * gv.w + bv.w;
        ushort4 ph, pl;
        unsigned short* php = (unsigned short*)&ph;
        unsigned short* plp = (unsigned short*)&pl;
        #pragma unroll
        for (int j = 0; j < 4; j++) {
            const unsigned hb = f2bf(o[j]);
            php[j] = (unsigned short)hb;
            plp[j] = (unsigned short)f2bf(o[j] - bf2f(hb));
        }
        *(ushort4*)&oh[(size_t)token * DMODEL + base] = ph;
        *(ushort4*)&ol[(size_t)token * DMODEL + base] = pl;
    }
}

// ---------------- fp32 -> bf16 hi/lo pair (elementwise) ----------------
__global__ __launch_bounds__(256)
void cvt_pair(const float* __restrict__ x, unsigned short* __restrict__ oh,
              unsigned short* __restrict__ ol)
{
    const int idx = (blockIdx.x * 256 + threadIdx.x) * 4;
    const float4 v = *(const float4*)&x[idx];
    const float va[4] = {v.x, v.y, v.z, v.w};
    ushort4 ph, pl;
    unsigned short* php = (unsigned short*)&ph;
    unsigned short* plp = (unsigned short*)&pl;
    #pragma unroll
    for (int j = 0; j < 4; j++) {
        const unsigned hb = f2bf(va[j]);
        php[j] = (unsigned short)hb;
        plp[j] = (unsigned short)f2bf(va[j] - bf2f(hb));
    }
    *(ushort4*)&oh[idx] = ph;
    *(ushort4*)&ol[idx] = pl;
}

// ---------------- concat [x | mask] -> bf16 pair, [4096][1024] ----------------
__global__ __launch_bounds__(256)
void cvt_cat(const float* __restrict__ x, const float* __restrict__ mask,
             unsigned short* __restrict__ oh, unsigned short* __restrict__ ol)
{
    const int idx = (blockIdx.x * 256 + threadIdx.x) * 4;
    const int row = idx >> 10, col = idx & 1023;
    const float* src = (col < 512) ? &x[(size_t)row * 512 + col]
                                   : &mask[(size_t)row * 512 + col - 512];
    const float4 v = *(const float4*)src;
    const float va[4] = {v.x, v.y, v.z, v.w};
    ushort4 ph, pl;
    unsigned short* php = (unsigned short*)&ph;
    unsigned short* plp = (unsigned short*)&pl;
    #pragma unroll
    for (int j = 0; j < 4; j++) {
        const unsigned hb = f2bf(va[j]);
        php[j] = (unsigned short)hb;
        plp[j] = (unsigned short)f2bf(va[j] - bf2f(hb));
    }
    *(ushort4*)&oh[idx] = ph;
    *(ushort4*)&ol[idx] = pl;
}

// ---------------- attention key-validity mask ----------------
__global__ __launch_bounds__(64)
void mask_kernel(const float* __restrict__ mask_in, float* __restrict__ mk)
{
    const int token = blockIdx.x;
    const int lane = threadIdx.x;
    const float* row = mask_in + (size_t)token * DMODEL;
    const float4 a = *(const float4*)&row[lane * 4];
    const float4 c = *(const float4*)&row[256 + lane * 4];
    float s = a.x + a.y + a.z + a.w + c.x + c.y + c.z + c.w;
    #pragma unroll
    for (int off = 1; off < 64; off <<= 1) s += __shfl_xor(s, off);
    if (lane == 0) mk[token] = (s > 0.f) ? 0.f : -1e9f;
}

// ---------------- relative position table E -> TILED f16 hi/lo ----------------
// Tiled layout for coalesced wave-loads in attn: for 16-row block g and s in {0,1},
//   Et[((g*2+s)*64 + l)*8 + j] = E[16*g + (l&15)][(l>>4)*8 + s*32 + j]
// so a wave (lane=l) fragment load is 1024B CONTIGUOUS. 2048 rows; row 2047
// duplicates row 2046 so the attn index gr in [0,2047] needs no clamp.
__global__ __launch_bounds__(64)
void e_kernel(const float* __restrict__ w1, const float* __restrict__ b1,
              const float* __restrict__ a1, const float* __restrict__ w2,
              const float* __restrict__ b2,
              unsigned short* __restrict__ Ehi, unsigned short* __restrict__ Elo)
{
    __shared__ float t1[DMODEL];
    const int r = blockIdx.x;              // 0..2047
    const int rr = (r > 2046) ? 2046 : r;  // row 2047 = copy of 2046
    const int lane = threadIdx.x;          // col 0..63
    const float rel = (float)rr - 1023.f;
    const float al = a1[0];
    for (int j = lane; j < DMODEL; j += 64) {
        float v = rel * w1[j] + b1[j];
        t1[j] = (v >= 0.f) ? v : al * v;
    }
    __syncthreads();
    float acc = b2[lane];
    for (int j = 0; j < DMODEL; j++)
        acc = fmaf(t1[j], w2[j * HDIM + lane], acc);
    // tiled address for (row=r, col=lane)
    const int g = r >> 4, s = lane >> 5;
    const int l = (((lane >> 3) & 3) << 4) | (r & 15);
    const int j = lane & 7;
    const size_t adr = ((size_t)(g * 2 + s) * 64 + l) * 8 + j;
    F16U t; t.h = (_Float16)acc;
    Ehi[adr] = t.u;
    Elo[adr] = f16u(acc - (float)t.h);
}

// ---------------- keyframe encoder layer 1 (K=2) -> bf16 pair ----------------
__global__ __launch_bounds__(256)
void kf1_kernel(const float* __restrict__ p, const float* __restrict__ w1,
                const float* __restrict__ b1, const float* __restrict__ a1,
                unsigned short* __restrict__ oh, unsigned short* __restrict__ ol)
{
    const int idx = blockIdx.x * 256 + threadIdx.x;
    const int m = idx >> 9, n = idx & 511;
    float v = fmaf(p[m*2], w1[n], fmaf(p[m*2+1], w1[DMODEL + n], b1[n]));
    v = (v >= 0.f) ? v : a1[0] * v;
    const unsigned hb = f2bf(v);
    oh[idx] = (unsigned short)hb;
    ol[idx] = (unsigned short)f2bf(v - bf2f(hb));
}

// ---------------- MFMA flash attention: 128-row Q-block, 8 waves, split-K -------
// R13-verified structure (83.5us, spill-free): SPLITK=2, 512 blocks = one
// 2-blocks/CU residency round, K/V LDS-staged with small reg prefetch,
// tiled-E coalesced loads, 2-chunk rel-term, fence-free P roundtrip.
__global__ __launch_bounds__(512, 2)
void attn_mfma(const _Float16* __restrict__ qhg, const _Float16* __restrict__ qmg,
               const _Float16* __restrict__ kg, const _Float16* __restrict__ vth,
               const _Float16* __restrict__ vtl, const _Float16* __restrict__ Ehi,
               const _Float16* __restrict__ Elo, const float* __restrict__ mk,
               float* __restrict__ Opart, float* __restrict__ Mpart,
               float* __restrict__ Lpart)
{
    __shared__ __align__(16) _Float16 Ks [64*LDS_STRIDE];
    __shared__ __align__(16) _Float16 Vhs[64*LDS_STRIDE];
    __shared__ __align__(16) _Float16 Vls[64*LDS_STRIDE];
    __shared__ __align__(16) _Float16 Phs[128*LDS_STRIDE];
    __shared__ __align__(16) _Float16 Pls[128*LDS_STRIDE];

    const int tid = threadIdx.x;
    const int lane = tid & 63;
    const int w = tid >> 6;                 // 0..7
    const int quad = lane >> 4;
    const int c = lane & 15;
    const int q0 = (blockIdx.x >> 1) * 128; // 128-row q-block (SPLITK=2)
    const int split = blockIdx.x & 1;
    const int hh = blockIdx.y;
    const int bb = blockIdx.z;
    const size_t base = (size_t)bb * TT * DMODEL + (size_t)hh * HDIM;
    const size_t vbase = (size_t)(bb * NHEAD + hh) * HDIM * TT;
    const float* mkp = mk + bb * TT;
    const int srow = tid >> 3;              // staging: 8 threads/row, 64 rows
    const int scol = (tid & 7) * 8;         // 16B each, 128B contiguous per row

    f16x8 qh[2], qm[2];
    {
        const size_t qrow = base + (size_t)(q0 + 16 * w + c) * DMODEL;
        #pragma unroll
        for (int s = 0; s < 2; s++) {
            qh[s] = *(const f16x8*)&qhg[qrow + s * 32 + quad * 8];
            qm[s] = *(const f16x8*)&qmg[qrow + s * 32 + quad * 8];
        }
    }

    f32x4 O[4];
    #pragma unroll
    for (int dt = 0; dt < 4; dt++) { O[dt][0]=0.f; O[dt][1]=0.f; O[dt][2]=0.f; O[dt][3]=0.f; }
    float mrun[4] = {-1e30f, -1e30f, -1e30f, -1e30f};
    float lrun[4] = {0.f, 0.f, 0.f, 0.f};
    const int Jb = 48 - 16 * w;             // negative for w>=4; gr stays >= 0

    const int ktlo = split * (16 / SPLITK);
    // prefetch tile ktlo staging into registers (small: 3x16B/thread, R7-proven)
    f16x8 sk, svh, svl;
    {
        const int k0 = ktlo * 64;
        sk  = *(const f16x8*)&kg [base + (size_t)(k0 + srow) * DMODEL + scol];
        svh = *(const f16x8*)&vth[vbase + (size_t)srow * TT + k0 + scol];
        svl = *(const f16x8*)&vtl[vbase + (size_t)srow * TT + k0 + scol];
    }
    for (int kt = ktlo; kt < ktlo + (16 / SPLITK); kt++) {
        const int k0 = kt * 64;
        const int rbase = k0 - q0 + 960;

        // write staged tile, then prefetch next tile's regs (flies under compute)
        *(f16x8*)&Ks [srow * LDS_STRIDE + scol] = sk;
        *(f16x8*)&Vhs[srow * LDS_STRIDE + scol] = svh;
        *(f16x8*)&Vls[srow * LDS_STRIDE + scol] = svl;
        __syncthreads();
        {
            const int kn = (kt + 1 < 16) ? (kt + 1) : kt;  // clamp: last prefetch unused
            const int k0n = kn * 64;
            sk  = *(const f16x8*)&kg [base + (size_t)(k0n + srow) * DMODEL + scol];
            svh = *(const f16x8*)&vth[vbase + (size_t)srow * TT + k0n + scol];
            svl = *(const f16x8*)&vtl[vbase + (size_t)srow * TT + k0n + scol];
        }

        // S = Q K^T (K fragments from LDS)
        f32x4 S[4];
        #pragma unroll
        for (int t = 0; t < 4; t++) { S[t][0]=0.f; S[t][1]=0.f; S[t][2]=0.f; S[t][3]=0.f; }
        #pragma unroll
        for (int t = 0; t < 4; t++) {
            const int ko = (16 * t + c) * LDS_STRIDE + quad * 8;
            #pragma unroll
            for (int s = 0; s < 2; s++) {
                const f16x8 kf = *(const f16x8*)&Ks[ko + s * 32];
                S[t] = MFMAH(qh[s], kf, S[t]);
            }
        }
        // rel term from TILED E, in two chunks (3u + 2u) to cap reg pressure.
        float bp[4][5];
        #pragma unroll
        for (int ch = 0; ch < 2; ch++) {
            const int u0 = ch * 3;
            const int nu = ch ? 2 : 3;
            f32x4 R[3], R2[3];
            #pragma unroll
            for (int v = 0; v < 3; v++) {
                if (v >= nu) continue;
                R[v][0]=0.f; R[v][1]=0.f; R[v][2]=0.f; R[v][3]=0.f;
                R2[v][0]=0.f; R2[v][1]=0.f; R2[v][2]=0.f; R2[v][3]=0.f;
            }
            #pragma unroll
            for (int v = 0; v < 3; v++) {
                if (v >= nu) continue;
                const int g = (rbase + Jb + 16 * (u0 + v)) >> 4;
                const size_t eb0 = ((size_t)(g * 2 + 0) * 64 + lane) * 8;
                const size_t eb1 = ((size_t)(g * 2 + 1) * 64 + lane) * 8;
                const f16x8 eh0 = *(const f16x8*)&Ehi[eb0];
                const f16x8 eh1 = *(const f16x8*)&Ehi[eb1];
                const f16x8 el0 = *(const f16x8*)&Elo[eb0];
                const f16x8 el1 = *(const f16x8*)&Elo[eb1];
                R[v]  = MFMAH(qh[0], eh0, R[v]);
                R[v]  = MFMAH(qh[1], eh1, R[v]);
                R[v]  = MFMAH(qh[0], el0, R[v]);
                R[v]  = MFMAH(qh[1], el1, R[v]);
                R2[v] = MFMAH(qm[0], eh0, R2[v]);
                R2[v] = MFMAH(qm[1], eh1, R2[v]);
            }
            #pragma unroll
            for (int v = 0; v < 3; v++) {
                if (v >= nu) continue;
                #pragma unroll
                for (int r = 0; r < 4; r++) {
                    const float rv = fmaf(R2[v][r], 9.765625e-4f, R[v][r]);
                    const int q = quad * 4 + r;
                    const int srcl = (quad << 4) | ((c - q + 15) & 15);
                    bp[r][u0 + v] = __int_as_float(__builtin_amdgcn_ds_bpermute(srcl << 2, __float_as_int(rv)));
                }
            }
        }
        float mkv[4];
        #pragma unroll
        for (int t = 0; t < 4; t++) mkv[t] = mkp[k0 + 16*t + c];
        float tmax[4] = {-3e38f, -3e38f, -3e38f, -3e38f};
        #pragma unroll
        for (int t = 0; t < 4; t++)
            #pragma unroll
            for (int r = 0; r < 4; r++) {
                const int q = quad*4 + r;
                const int jj = 16*t + c - q + 15;
                const float rv = ((jj >> 4) == t) ? bp[r][t] : bp[r][t+1];
                const float v = (S[t][r] + rv) * 0.125f + mkv[t];
                S[t][r] = v;
                tmax[r] = fmaxf(tmax[r], v);
            }
        #pragma unroll
        for (int r = 0; r < 4; r++) {
            tmax[r] = fmaxf(tmax[r], __shfl_xor(tmax[r], 1));
            tmax[r] = fmaxf(tmax[r], __shfl_xor(tmax[r], 2));
            tmax[r] = fmaxf(tmax[r], __shfl_xor(tmax[r], 4));
            tmax[r] = fmaxf(tmax[r], __shfl_xor(tmax[r], 8));
        }
        float corr[4];
        #pragma unroll
        for (int r = 0; r < 4; r++) {
            const float mn = fmaxf(mrun[r], tmax[r]);
            corr[r] = __expf(mrun[r] - mn);
            mrun[r] = mn;
            lrun[r] *= corr[r];
        }
        #pragma unroll
        for (int dt = 0; dt < 4; dt++)
            #pragma unroll
            for (int r = 0; r < 4; r++) O[dt][r] *= corr[r];
        float psum[4] = {0.f, 0.f, 0.f, 0.f};
        #pragma unroll
        for (int t = 0; t < 4; t++)
            #pragma unroll
            for (int r = 0; r < 4; r++) {
                const float p = __expf(S[t][r] - mrun[r]);
                psum[r] += p;
                const _Float16 hp = (_Float16)p;
                Phs[(w*16 + quad*4 + r)*LDS_STRIDE + 16*t + c] = hp;
                Pls[(w*16 + quad*4 + r)*LDS_STRIDE + 16*t + c] = (_Float16)(p - (float)hp);
            }
        #pragma unroll
        for (int r = 0; r < 4; r++) {
            psum[r] += __shfl_xor(psum[r], 1);
            psum[r] += __shfl_xor(psum[r], 2);
            psum[r] += __shfl_xor(psum[r], 4);
            psum[r] += __shfl_xor(psum[r], 8);
            lrun[r] += psum[r];
        }
        // P write -> P read: same-wave DS ordering + compiler-tracked aliasing
        // (fence-free correctness verified R5-R13).
        f16x8 pfh[2], pfl[2];
        #pragma unroll
        for (int s = 0; s < 2; s++) {
            pfh[s] = *(const f16x8*)&Phs[(w*16 + c)*LDS_STRIDE + s*32 + quad*8];
            pfl[s] = *(const f16x8*)&Pls[(w*16 + c)*LDS_STRIDE + s*32 + quad*8];
        }
        // O += P V (V fragments from LDS)
        #pragma unroll
        for (int dt = 0; dt < 4; dt++) {
            const int vo = (16 * dt + c) * LDS_STRIDE + quad * 8;
            #pragma unroll
            for (int s = 0; s < 2; s++) {
                const f16x8 vhf = *(const f16x8*)&Vhs[vo + s * 32];
                const f16x8 vlf = *(const f16x8*)&Vls[vo + s * 32];
                O[dt] = MFMAH(pfh[s], vhf, O[dt]);
                O[dt] = MFMAH(pfl[s], vhf, O[dt]);
                O[dt] = MFMAH(pfh[s], vlf, O[dt]);
            }
        }
        __syncthreads();   // all waves done with Ks/Vhs/Vls before next overwrite
    }
    // write partial: unnormalized O (f32) + m,l per q-row
    const size_t obase = (size_t)((split * BB + bb) * NHEAD + hh) * TT + q0 + 16 * w;
    #pragma unroll
    for (int r = 0; r < 4; r++) {
        if (c == 0) {
            Mpart[obase + quad * 4 + r] = mrun[r];
            Lpart[obase + quad * 4 + r] = lrun[r];
        }
    }
    #pragma unroll
    for (int dt = 0; dt < 4; dt++)
        #pragma unroll
        for (int r = 0; r < 4; r++)
            Opart[(obase + quad * 4 + r) * HDIM + 16 * dt + c] = O[dt][r];
}

// ---------------- combine SPLITK attention partials -> bf16 hi/lo ----------------
__global__ __launch_bounds__(256)
void attn_combine(const float* __restrict__ Opart, const float* __restrict__ Mpart,
                  const float* __restrict__ Lpart,
                  unsigned short* __restrict__ obh, unsigned short* __restrict__ obl)
{
    const int tid = threadIdx.x;
    const int row = blockIdx.x * 16 + (tid >> 4);   // (bb*H+hh)*T + q
    const int d0 = (tid & 15) * 4;
    const int SR = BB * NHEAD * TT;
    float mv[SPLITK];
    float m = -3e38f;
    #pragma unroll
    for (int i = 0; i < SPLITK; i++) { mv[i] = Mpart[i * SR + row]; m = fmaxf(m, mv[i]); }
    float wv[SPLITK];
    float l = 0.f;
    #pragma unroll
    for (int i = 0; i < SPLITK; i++) {
        wv[i] = __expf(mv[i] - m);
        l += wv[i] * Lpart[i * SR + row];
    }
    const float inv = 1.f / l;
    float o[4] = {0.f, 0.f, 0.f, 0.f};
    #pragma unroll
    for (int i = 0; i < SPLITK; i++) {
        const float4 v = *(const float4*)&Opart[((size_t)i * SR + row) * HDIM + d0];
        o[0] = fmaf(wv[i], v.x, o[0]);
        o[1] = fmaf(wv[i], v.y, o[1]);
        o[2] = fmaf(wv[i], v.z, o[2]);
        o[3] = fmaf(wv[i], v.w, o[3]);
    }
    const int q = row & (TT - 1), bh = row >> 10;
    const size_t oix = ((size_t)((bh >> 3) * TT + q)) * DMODEL + (size_t)(bh & 7) * HDIM + d0;
    ushort4 ph, pl;
    unsigned short* php = (unsigned short*)&ph;
    unsigned short* plp = (unsigned short*)&pl;
    #pragma unroll
    for (int j = 0; j < 4; j++) {
        const float v = o[j] * inv;
        const unsigned hb = f2bf(v);
        php[j] = (unsigned short)hb;
        plp[j] = (unsigned short)f2bf(v - bf2f(hb));
    }
    *(ushort4*)&obh[oix] = ph;
    *(ushort4*)&obl[oix] = pl;
}

extern "C" void kernel_launch(void* const* d_in, const int* in_sizes, int n_in,
                              void* d_out, int out_size, void* d_ws, size_t ws_size,
                              hipStream_t stream)
{
    const float* x       = (const float*)d_in[0];
    const float* mask_in = (const float*)d_in[1];
    const float* p_kf    = (const float*)d_in[2];
    const float* enc_w1  = (const float*)d_in[3];
    const float* enc_b1  = (const float*)d_in[4];
    const float* enc_a1  = (const float*)d_in[5];
    const float* enc_w2  = (const float*)d_in[6];
    const float* enc_b2  = (const float*)d_in[7];
    const float* enc_a2  = (const float*)d_in[8];
    const float* kf_w1   = (const float*)d_in[9];
    const float* kf_b1   = (const float*)d_in[10];
    const float* kf_a    = (const float*)d_in[11];
    const float* kf_w2   = (const float*)d_in[12];
    const float* kf_b2   = (const float*)d_in[13];
    const float* rel_w1  = (const float*)d_in[14];
    const float* rel_b1  = (const float*)d_in[15];
    const float* rel_a   = (const float*)d_in[16];
    const float* rel_w2  = (const float*)d_in[17];
    const float* rel_b2  = (const float*)d_in[18];
    const float* ln_g    = (const float*)d_in[19];
    const float* ln_b    = (const float*)d_in[20];
    const float* wq      = (const float*)d_in[21];
    const float* wk      = (const float*)d_in[22];
    const float* wv      = (const float*)d_in[23];
    const float* wo      = (const float*)d_in[24];
    const float* wob     = (const float*)d_in[25];
    const float* fw1     = (const float*)d_in[26];
    const float* fb1     = (const float*)d_in[27];
    const float* fa      = (const float*)d_in[28];
    const float* fw2     = (const float*)d_in[29];
    const float* fb2     = (const float*)d_in[30];
    const float* dw1     = (const float*)d_in[31];
    const float* db1     = (const float*)d_in[32];
    const float* da      = (const float*)d_in[33];
    const float* dw2     = (const float*)d_in[34];
    const float* db2     = (const float*)d_in[35];
    float* out = (float*)d_out;

    // ---- workspace layout (bytes), total ~88.6 MB ----
    char* p = (char*)d_ws;
    const size_t SZ_TD  = (size_t)NTOK * DMODEL;      // 2M elems
    float* h = (float*)p;                 p += SZ_TD * 4;
    unsigned short* hnh = (unsigned short*)p; p += SZ_TD * 2;
    unsigned short* hnl = (unsigned short*)p; p += SZ_TD * 2;
    unsigned short* qhg = (unsigned short*)p; p += SZ_TD * 2;
    unsigned short* qmg = (unsigned short*)p; p += SZ_TD * 2;
    unsigned short* kg  = (unsigned short*)p; p += SZ_TD * 2;
    unsigned short* vhg = (unsigned short*)p; p += SZ_TD * 2;   // V^T hi planes
    unsigned short* vlg = (unsigned short*)p; p += SZ_TD * 2;   // V^T lo planes
    unsigned short* obh = (unsigned short*)p; p += SZ_TD * 2;
    unsigned short* obl = (unsigned short*)p; p += SZ_TD * 2;
    unsigned short* midh = (unsigned short*)p; p += (size_t)NTOK * DFF * 2;
    unsigned short* midl = (unsigned short*)p; p += (size_t)NTOK * DFF * 2;
    unsigned short* Ehi = (unsigned short*)p; p += (size_t)2048 * HDIM * 2;   // TILED layout
    unsigned short* Elo = (unsigned short*)p; p += (size_t)2048 * HDIM * 2;   // TILED layout
    float* mk = (float*)p;                p += (size_t)NTOK * 4;
    unsigned short* qkvh = (unsigned short*)p; p += (size_t)1536 * 512 * 2;
    unsigned short* qkvl = (unsigned short*)p; p += (size_t)1536 * 512 * 2;
    unsigned short* woh  = (unsigned short*)p; p += (size_t)512 * 512 * 2;
    unsigned short* wol  = (unsigned short*)p; p += (size_t)512 * 512 * 2;
    unsigned short* f1h  = (unsigned short*)p; p += (size_t)2048 * 512 * 2;
    unsigned short* f1l  = (unsigned short*)p; p += (size_t)2048 * 512 * 2;
    unsigned short* f2h  = (unsigned short*)p; p += (size_t)512 * 2048 * 2;
    unsigned short* f2l  = (unsigned short*)p; p += (size_t)512 * 2048 * 2;
    float* pe = (float*)obh;   // 8 MB spanning obh+obl (free during encode)
    // split-K attention scratch (aliases buffers dead during attention)
    float* Opart = (float*)midh;
    float* Mpart = (float*)hnh;
    float* Lpart = Mpart + (size_t)SPLITK * BB * NHEAD * TT;

    const dim3 blk256(256), blk64(64), blk512(512);
    const dim3 gN512(8, 64);
    const dim3 gQKV(24, 64);
    const dim3 gFFN1(32, 64);
    const dim3 gN256(4, 64);
    #define NP nullptr

    e_kernel<<<dim3(2048), blk64, 0, stream>>>(rel_w1, rel_b1, rel_a, rel_w2, rel_b2, Ehi, Elo);
    mask_kernel<<<dim3(NTOK), blk64, 0, stream>>>(mask_in, mk);
    wcvt<<<dim3(8, 8), blk256, 0, stream>>>(kf_w2, woh, wol, 512, 512);
    wcvt<<<dim3(8, 16), blk256, 0, stream>>>(enc_w1, f1h, f1l, 512, 1024);
    wcvt<<<dim3(8, 8), blk256, 0, stream>>>(enc_w2, qkvh, qkvl, 512, 512);
    kf1_kernel<<<dim3(NTOK*DMODEL/256), blk256, 0, stream>>>(p_kf, kf_w1, kf_b1, kf_a, qhg, qmg);
    gemm_l<<<gN512, blk256, 0, stream>>>(qhg, qmg, woh, wol, kf_b2, NP, NP, pe,
                                         NP, NP, NP, NP, NP, DMODEL, DMODEL, MODE_F32);
    cvt_cat<<<dim3(NTOK*1024/1024), blk256, 0, stream>>>(x, mask_in, midh, midl);
    gemm_l<<<gN512, blk256, 0, stream>>>(midh, midl, f1h, f1l, enc_b1, enc_a1, NP, NP,
                                         hnh, hnl, NP, NP, NP, DMODEL, 2*DMODEL, MODE_BF);
    gemm_l<<<gN512, blk256, 0, stream>>>(hnh, hnl, qkvh, qkvl, enc_b2, enc_a2, pe, h,
                                         NP, NP, NP, NP, NP, DMODEL, DMODEL, MODE_F32);

    for (int i = 0; i < NLAYER; i++) {
        const size_t wofs = (size_t)i * DMODEL * DMODEL;
        wcvt6<<<dim3(768), blk256, 0, stream>>>(
            wq + wofs, wk + wofs, wv + wofs, wo + wofs,
            fw1 + (size_t)i*DMODEL*DFF, fw2 + (size_t)i*DFF*DMODEL,
            qkvh, qkvl, woh, wol, f1h, f1l, f2h, f2l);

        ln_kernel<<<dim3(NTOK), blk64, 0, stream>>>(h, ln_g, ln_b, hnh, hnl);
        gemm_l<<<gQKV, blk256, 0, stream>>>(hnh, hnl, qkvh, qkvl, NP, NP, NP, NP,
                                            qhg, qmg, kg, vhg, vlg, 1536, DMODEL, MODE_QKV);
        attn_mfma<<<dim3((TT/128)*SPLITK, NHEAD, BB), blk512, 0, stream>>>(
            (const _Float16*)qhg, (const _Float16*)qmg, (const _Float16*)kg,
            (const _Float16*)vhg, (const _Float16*)vlg,
            (const _Float16*)Ehi, (const _Float16*)Elo, mk, Opart, Mpart, Lpart);
        attn_combine<<<dim3(BB*NHEAD*TT/16), blk256, 0, stream>>>(Opart, Mpart, Lpart, obh, obl);
        gemm_l<<<gN512, blk256, 0, stream>>>(obh, obl, woh, wol, wob + (size_t)i*DMODEL,
                                             NP, h, h, NP, NP, NP, NP, NP, DMODEL, DMODEL, MODE_F32);
        ln_kernel<<<dim3(NTOK), blk64, 0, stream>>>(h, ln_g, ln_b, hnh, hnl);
        gemm_l<<<gFFN1, blk256, 0, stream>>>(hnh, hnl, f1h, f1l, fb1 + (size_t)i*DFF, fa + i,
                                             NP, NP, midh, midl, NP, NP, NP, DFF, DMODEL, MODE_BF);
        gemm_l<<<gN512, blk256, 0, stream>>>(midh, midl, f2h, f2l, fb2 + (size_t)i*DMODEL,
                                             NP, h, h, NP, NP, NP, NP, NP, DMODEL, DFF, MODE_F32);
    }
    wcvt<<<dim3(8, 8), blk256, 0, stream>>>(dw1, woh, wol, 512, 512);
    wcvt<<<dim3(4, 8), blk256, 0, stream>>>(dw2, f2h, f2l, 256, 512);
    cvt_pair<<<dim3(SZ_TD/1024), blk256, 0, stream>>>(h, hnh, hnl);
    gemm_l<<<gN512, blk256, 0, stream>>>(hnh, hnl, woh, wol, db1, da, NP, NP,
                                         midh, midl, NP, NP, NP, DMODEL, DMODEL, MODE_BF);
    gemm_l<<<gN256, blk256, 0, stream>>>(midh, midl, f2h, f2l, db2, NP, NP, out,
                                         NP, NP, NP, NP, NP, MFOUT, DMODEL, MODE_F32);
    #undef NP
}